// Round 10
// baseline (408.086 us; speedup 1.0000x reference)
//
#include <hip/hip_runtime.h>

#define NN 2048
#define CC 512
#define BB 4
#define HH 8
#define DD 64
#define SCALE 0.18033688011112043f   // 0.125 * log2(e), folded into Wq/bq

typedef unsigned short u16;
typedef __attribute__((ext_vector_type(8))) short bf16x8;   // 8 bf16 (4 VGPRs)
typedef __attribute__((ext_vector_type(4))) short bf16x4;   // 4 bf16 (2 VGPRs)
typedef __attribute__((ext_vector_type(4))) float f32x4;    // MFMA accumulator

extern "C" __device__ float __ocml_native_exp2_f32(float);  // bare v_exp_f32

#if __has_builtin(__builtin_amdgcn_mfma_f32_16x16x16bf16_1k)
#define MFMA16(A, B, C) __builtin_amdgcn_mfma_f32_16x16x16bf16_1k(A, B, C, 0, 0, 0)
#else
__device__ __forceinline__ f32x4 mfma16_asm(bf16x4 a, bf16x4 b, f32x4 c) {
    f32x4 d;
    asm("v_mfma_f32_16x16x16_bf16 %0, %1, %2, %3" : "=v"(d) : "v"(a), "v"(b), "0"(c));
    return d;
}
#define MFMA16(A, B, C) mfma16_asm(A, B, C)
#endif

__device__ inline u16 f2b(float x) {           // fp32 -> bf16 (RNE)
    unsigned u = __builtin_bit_cast(unsigned, x);
    u += 0x7fffu + ((u >> 16) & 1u);
    return (u16)(u >> 16);
}
__device__ inline float b2f(u16 h) {
    unsigned u = ((unsigned)h) << 16;
    return __builtin_bit_cast(float, u);
}

#define GLD16(g, l) __builtin_amdgcn_global_load_lds( \
    (const __attribute__((address_space(1))) unsigned int*)(g), \
    (__attribute__((address_space(3))) unsigned int*)(l), 16, 0, 0)

// ---------------------------------------------------------------------------
// 4-wave GEMM core (M / W2 path): 128(n) x (JT*32)(o) x 64(k), dbuf option.
// XOR-swizzled 16B granules — conflict-free ds_read_b128.
// ---------------------------------------------------------------------------
template<int JT, bool DBUF>
__device__ __forceinline__ void gemm_core_t(
    const u16* __restrict__ Xa, const u16* __restrict__ Xb, int Ca, int K,
    const u16* __restrict__ Wt, size_t rowBase,
    u16* As, u16* Bs, f32x4 (&acc)[4][JT])
{
    constexpr int OT = JT * 32;
    constexpr int ASZ = 128 * 64, BSZ = OT * 64;
    const int tid = threadIdx.x;
    const int lane = tid & 63, w = tid >> 6;
    const int quad = lane >> 4, l16 = lane & 15;
    const int wrow = w & 1, wcol = w >> 1;
    const int arow = lane >> 3, aseg = lane & 7;   // 8 rows x 8x16B per GLD set
    const int asw = aseg ^ arow;                   // pre-swizzled source granule
    const int lk = l16 & 7;                        // read-side swizzle key

    auto stage = [&](int k0, u16* Ad, u16* Bd) {
        const u16* Xs; int Crow, cc;
        if (k0 < Ca) { Xs = Xa; Crow = Ca; cc = k0; }
        else         { Xs = Xb; Crow = K - Ca; cc = k0 - Ca; }
#pragma unroll
        for (int i = 0; i < 4; ++i) {
            int rl = w * 32 + i * 8 + arow;
            int la = __builtin_amdgcn_readfirstlane((w * 32 + i * 8) * 64);
            GLD16(Xs + (rowBase + rl) * (size_t)Crow + cc + asw * 8, (char*)Ad + (size_t)la * 2);
        }
#pragma unroll
        for (int i = 0; i < OT / 32; ++i) {
            int rl = w * (OT / 4) + i * 8 + arow;
            int la = __builtin_amdgcn_readfirstlane((w * (OT / 4) + i * 8) * 64);
            GLD16(Wt + (size_t)rl * K + k0 + asw * 8, (char*)Bd + (size_t)la * 2);
        }
    };
    auto compute = [&](const u16* Ac, const u16* Bc) {
#pragma unroll
        for (int kk = 0; kk < 2; ++kk) {
            const int g = ((kk * 4 + quad) ^ lk) * 8;
            bf16x8 av[4], bv[JT];
#pragma unroll
            for (int i = 0; i < 4; ++i)
                av[i] = *(const bf16x8*)&Ac[(wrow * 64 + i * 16 + l16) * 64 + g];
#pragma unroll
            for (int jj = 0; jj < JT; ++jj)
                bv[jj] = *(const bf16x8*)&Bc[(wcol * JT * 16 + jj * 16 + l16) * 64 + g];
#pragma unroll
            for (int i = 0; i < 4; ++i)
#pragma unroll
                for (int jj = 0; jj < JT; ++jj)
                    acc[i][jj] = __builtin_amdgcn_mfma_f32_16x16x32_bf16(av[i], bv[jj], acc[i][jj], 0, 0, 0);
        }
    };

    if constexpr (DBUF) {
        stage(0, As, Bs);
        const int nt = K / 64;
        for (int t = 0; t < nt; ++t) {
            const u16* Ac = As + (t & 1) * ASZ;
            const u16* Bc = Bs + (t & 1) * BSZ;
            __syncthreads();
            if (t + 1 < nt)
                stage((t + 1) * 64, As + ((t + 1) & 1) * ASZ, Bs + ((t + 1) & 1) * BSZ);
            compute(Ac, Bc);
        }
    } else {
        for (int k0 = 0; k0 < K; k0 += 64) {
            stage(k0, As, Bs);
            __syncthreads();
            compute(As, Bs);
            __syncthreads();
        }
    }
}

// mode 0: outB bf16 [B,N,Cout]
// mode 1: outB bf16 [B,H,D,N] (o=(h<<6)|d)
// mode 2: outF fp32 [B,Cout,N]=acc+bias+res AND outB bf16 [B,N,Cout]
// mode 3: outF only
template<int JT>
__device__ __forceinline__ void gemm_epilogue_t(
    f32x4 (&acc)[4][JT], const float* __restrict__ bias, int mode,
    int b, int n0, int o0, int Cout,
    const float* __restrict__ res, float* __restrict__ outF, u16* __restrict__ outB)
{
    const int tid = threadIdx.x;
    const int lane = tid & 63, w = tid >> 6;
    const int quad = lane >> 4, l16 = lane & 15;
    const int wrow = w & 1, wcol = w >> 1;
    const size_t bN = (size_t)b * NN;
    const int nb0 = n0 + wrow * 64, ob0 = o0 + wcol * JT * 16;

    if (mode == 0) {
#pragma unroll
        for (int j = 0; j < JT; ++j) {
            int o = ob0 + j * 16 + l16;
            float bs = bias[o];
#pragma unroll
            for (int i = 0; i < 4; ++i)
#pragma unroll
                for (int r = 0; r < 4; ++r) {
                    int n = nb0 + i * 16 + quad * 4 + r;
                    outB[(bN + n) * Cout + o] = f2b(acc[i][j][r] + bs);
                }
        }
    } else if (mode == 1) {
#pragma unroll
        for (int j = 0; j < JT; ++j) {
            int o = ob0 + j * 16 + l16;
            float bs = bias[o];
            int h = o >> 6, d = o & 63;
#pragma unroll
            for (int i = 0; i < 4; ++i) {
                int n = nb0 + i * 16 + quad * 4;
                ushort4 pk;
                pk.x = f2b(acc[i][j][0] + bs); pk.y = f2b(acc[i][j][1] + bs);
                pk.z = f2b(acc[i][j][2] + bs); pk.w = f2b(acc[i][j][3] + bs);
                *(ushort4*)&outB[(((size_t)b * HH + h) * DD + d) * NN + n] = pk;
            }
        }
    } else {
#pragma unroll
        for (int j = 0; j < JT; ++j) {
            int o = ob0 + j * 16 + l16;
            float bs = bias[o];
#pragma unroll
            for (int i = 0; i < 4; ++i) {
                int n = nb0 + i * 16 + quad * 4;
                size_t ad = ((size_t)b * Cout + o) * NN + n;
                float4 rv = *(const float4*)&res[ad];
                float4 yv;
                yv.x = acc[i][j][0] + bs + rv.x;
                yv.y = acc[i][j][1] + bs + rv.y;
                yv.z = acc[i][j][2] + bs + rv.z;
                yv.w = acc[i][j][3] + bs + rv.w;
                *(float4*)&outF[ad] = yv;
                if (mode == 2) {
                    outB[(bN + n + 0) * Cout + o] = f2b(yv.x);
                    outB[(bN + n + 1) * Cout + o] = f2b(yv.y);
                    outB[(bN + n + 2) * Cout + o] = f2b(yv.z);
                    outB[(bN + n + 3) * Cout + o] = f2b(yv.w);
                }
            }
        }
    }
}

template<int JT>
__global__ __launch_bounds__(256, 3) void gemm_bf16_t(
    const u16* __restrict__ Wb, const float* __restrict__ bias,
    const u16* __restrict__ Xa, const u16* __restrict__ Xb,
    int Ca, int K, int Cout,
    const float* __restrict__ res, float* __restrict__ outF,
    u16* __restrict__ outB, int mode)
{
    __shared__ u16 As[2 * 128 * 64];
    __shared__ u16 Bs[2 * JT * 32 * 64];
    const int b = blockIdx.z, n0 = blockIdx.x * 128, o0 = blockIdx.y * (JT * 32);
    f32x4 acc[4][JT] = {};
    gemm_core_t<JT, true>(Xa, Xb, Ca, K, Wb + (size_t)o0 * K, (size_t)b * NN + n0, As, Bs, acc);
    gemm_epilogue_t<JT>(acc, bias, mode, b, n0, o0, Cout, res, outF, outB);
}

// ---------------------------------------------------------------------------
// 8-wave GEMM core (QKV / W1 path): 128(n) x 128(o) x 64(k) per block.
// ---------------------------------------------------------------------------
template<bool DBUF>
__device__ __forceinline__ void gemm_core8(
    const u16* __restrict__ Xa, const u16* __restrict__ Xb, int Ca, int K,
    const u16* __restrict__ Wt, size_t rowBase,
    u16* As, u16* Bs, f32x4 (&acc)[4][2])
{
    constexpr int ASZ = 128 * 64, BSZ = 128 * 64;
    const int tid = threadIdx.x;
    const int lane = tid & 63, w = tid >> 6;
    const int quad = lane >> 4, l16 = lane & 15;
    const int wr = w & 1, wc = w >> 1;
    const int arow = lane >> 3, aseg = lane & 7;
    const int asw = aseg ^ arow;
    const int lk = l16 & 7;

    auto stage = [&](int k0, u16* Ad, u16* Bd) {
        const u16* Xs; int Crow, cc;
        if (k0 < Ca) { Xs = Xa; Crow = Ca; cc = k0; }
        else         { Xs = Xb; Crow = K - Ca; cc = k0 - Ca; }
#pragma unroll
        for (int i = 0; i < 2; ++i) {
            int rl = w * 16 + i * 8 + arow;
            int la = __builtin_amdgcn_readfirstlane((w * 16 + i * 8) * 64);
            GLD16(Xs + (rowBase + rl) * (size_t)Crow + cc + asw * 8, (char*)Ad + (size_t)la * 2);
            GLD16(Wt + (size_t)rl * K + k0 + asw * 8, (char*)Bd + (size_t)la * 2);
        }
    };
    auto compute = [&](const u16* Ac, const u16* Bc) {
#pragma unroll
        for (int kk = 0; kk < 2; ++kk) {
            const int g = ((kk * 4 + quad) ^ lk) * 8;
            bf16x8 av[4], bv[2];
#pragma unroll
            for (int i = 0; i < 4; ++i)
                av[i] = *(const bf16x8*)&Ac[(wr * 64 + i * 16 + l16) * 64 + g];
#pragma unroll
            for (int j = 0; j < 2; ++j)
                bv[j] = *(const bf16x8*)&Bc[(wc * 32 + j * 16 + l16) * 64 + g];
#pragma unroll
            for (int i = 0; i < 4; ++i)
#pragma unroll
                for (int j = 0; j < 2; ++j)
                    acc[i][j] = __builtin_amdgcn_mfma_f32_16x16x32_bf16(av[i], bv[j], acc[i][j], 0, 0, 0);
        }
    };

    if constexpr (DBUF) {
        stage(0, As, Bs);
        const int nt = K / 64;
        for (int t = 0; t < nt; ++t) {
            const u16* Ac = As + (t & 1) * ASZ;
            const u16* Bc = Bs + (t & 1) * BSZ;
            __syncthreads();
            if (t + 1 < nt)
                stage((t + 1) * 64, As + ((t + 1) & 1) * ASZ, Bs + ((t + 1) & 1) * BSZ);
            compute(Ac, Bc);
        }
    } else {
        for (int k0 = 0; k0 < K; k0 += 64) {
            stage(k0, As, Bs);
            __syncthreads();
            compute(As, Bs);
            __syncthreads();
        }
    }
}

// modes 0/1 (QKV path)
__device__ __forceinline__ void gemm_epilogue8(
    f32x4 (&acc)[4][2], const float* __restrict__ bias, int mode,
    int b, int n0, int o0, int Cout, u16* __restrict__ outB)
{
    const int tid = threadIdx.x;
    const int lane = tid & 63, w = tid >> 6;
    const int quad = lane >> 4, l16 = lane & 15;
    const int wr = w & 1, wc = w >> 1;
    const size_t bN = (size_t)b * NN;
    const int nb0 = n0 + wr * 64, ob0 = o0 + wc * 32;

    if (mode == 0) {
#pragma unroll
        for (int j = 0; j < 2; ++j) {
            int o = ob0 + j * 16 + l16;
            float bs = bias[o];
#pragma unroll
            for (int i = 0; i < 4; ++i)
#pragma unroll
                for (int r = 0; r < 4; ++r) {
                    int n = nb0 + i * 16 + quad * 4 + r;
                    outB[(bN + n) * Cout + o] = f2b(acc[i][j][r] + bs);
                }
        }
    } else {
#pragma unroll
        for (int j = 0; j < 2; ++j) {
            int o = ob0 + j * 16 + l16;
            float bs = bias[o];
            int h = o >> 6, d = o & 63;
#pragma unroll
            for (int i = 0; i < 4; ++i) {
                int n = nb0 + i * 16 + quad * 4;
                ushort4 pk;
                pk.x = f2b(acc[i][j][0] + bs); pk.y = f2b(acc[i][j][1] + bs);
                pk.z = f2b(acc[i][j][2] + bs); pk.w = f2b(acc[i][j][3] + bs);
                *(ushort4*)&outB[(((size_t)b * HH + h) * DD + d) * NN + n] = pk;
            }
        }
    }
}

// Fused Q+K+V, 8-wave dbuf: yb<4 -> Q from XQ; 4..7 -> K from XKV; 8..11 -> V.
__global__ __launch_bounds__(512, 4) void gemm_qkv(
    const u16* __restrict__ WQ, const float* __restrict__ bQ,
    const u16* __restrict__ XQ, u16* __restrict__ outQ,
    const u16* __restrict__ WK, const float* __restrict__ bK, u16* __restrict__ outK,
    const u16* __restrict__ WV, const float* __restrict__ bV, u16* __restrict__ outV,
    const u16* __restrict__ XKV)
{
    __shared__ u16 As[2 * 128 * 64];
    __shared__ u16 Bs[2 * 128 * 64];
    const int yb = blockIdx.y;
    const u16* W; const float* bias; const u16* X; u16* outB; int mode, o0;
    if (yb < 4)      { o0 = yb * 128;       W = WQ; bias = bQ; X = XQ;  outB = outQ; mode = 0; }
    else if (yb < 8) { o0 = (yb - 4) * 128; W = WK; bias = bK; X = XKV; outB = outK; mode = 0; }
    else             { o0 = (yb - 8) * 128; W = WV; bias = bV; X = XKV; outB = outV; mode = 1; }
    const int b = blockIdx.z, n0 = blockIdx.x * 128;
    f32x4 acc[4][2] = {};
    gemm_core8<true>(X, nullptr, 512, 512, W + (size_t)o0 * 512, (size_t)b * NN + n0, As, Bs, acc);
    gemm_epilogue8(acc, bias, mode, b, n0, o0, 512, outB);
}

// W1 GEMM, 8-wave dbuf, instance-norm statistics fused into the epilogue.
__global__ __launch_bounds__(512, 4) void gemm_w1(
    const u16* __restrict__ Wb, const float* __restrict__ bias,
    const u16* __restrict__ Xa, const u16* __restrict__ Xb,
    u16* __restrict__ outB, float* __restrict__ Ssum, float* __restrict__ Ssq)
{
    __shared__ u16 As[2 * 128 * 64];
    __shared__ u16 Bs[2 * 128 * 64];
    const int b = blockIdx.z, n0 = blockIdx.x * 128, o0 = blockIdx.y * 128;
    f32x4 acc[4][2] = {};
    gemm_core8<true>(Xa, Xb, 512, 1024, Wb + (size_t)o0 * 1024, (size_t)b * NN + n0, As, Bs, acc);

    const int tid = threadIdx.x;
    const int lane = tid & 63, w = tid >> 6;
    const int quad = lane >> 4, l16 = lane & 15;
    const int wr = w & 1, wc = w >> 1;
    const size_t bN = (size_t)b * NN;
    const int nb0 = n0 + wr * 64, ob0 = o0 + wc * 32;

#pragma unroll
    for (int j = 0; j < 2; ++j) {
        int o = ob0 + j * 16 + l16;
        float bs = bias[o];
        float s = 0.f, q = 0.f;
#pragma unroll
        for (int i = 0; i < 4; ++i)
#pragma unroll
            for (int r = 0; r < 4; ++r) {
                int n = nb0 + i * 16 + quad * 4 + r;
                float y = acc[i][j][r] + bs;
                s += y; q += y * y;
                outB[(bN + n) * 1024 + o] = f2b(y);
            }
        s += __shfl_xor(s, 16); s += __shfl_xor(s, 32);   // sum over quad -> 64 rows
        q += __shfl_xor(q, 16); q += __shfl_xor(q, 32);
        if (quad == 0) {
            atomicAdd(&Ssum[b * 1024 + o], s);
            atomicAdd(&Ssq[b * 1024 + o], q);
        }
    }
}

// ---------------------------------------------------------------------------
// Flash attention, MFMA, no max-shift (scores O(1), softmax shift-invariant).
// Q pre-scaled by 0.125*log2e at weight-prep -> p = exp2(s) directly.
// R10: kv-split 4 + 4-wave blocks + P ENTIRELY IN REGISTERS.
// Each wave owns a 16-kv-row quarter (hv); QK's C-fragment places
// S^T[m=hv*16+quad*4+r][n=l16] exactly where PV's mfma_16x16x16 A-operand
// needs P[n=l16][k=quad*4+j] (r=j) -> exp2 results pack straight into the
// PV A-operand. P LDS round-trip (32KB/tile) eliminated. Waves read their
// K/V quarters exactly once (amplification 4x -> 1x): per-tile DS traffic
// 112KB -> 32KB. qs=4 (64 q-cols/wave), 64 q-rows/block, grid 1024
// (XCD-swizzled, 4 heads/XCD), ~3 blocks/CU. l via scalar partial sums +
// epilogue shuffle/LDS transpose (replaces the lacc MFMAs). O/l partials
// of the 4 kv-quarters merged via a 2-round LDS tree at the end.
// ---------------------------------------------------------------------------
__global__ __launch_bounds__(256, 3) void attn(
    const u16* __restrict__ Qg, const u16* __restrict__ Kg,
    const u16* __restrict__ Vg, u16* __restrict__ Og)
{
    // loop phase: Ks dbuf 2x(64x64) + Vt dbuf 2x(64x64) = 32KB
    // merge phase (reuses pool): 2 slots x 64 lanes x 68 floats + lbuf
    __shared__ __align__(16) u16 pool[17664];
    u16* const Ksb[2] = { pool, pool + 4096 };
    u16* const Vtb[2] = { pool + 2 * 4096, pool + 3 * 4096 };
    const int tid = threadIdx.x;
    const int lane = tid & 63, hv = tid >> 6;      // 4 waves = 4 kv-quarters
    const int quad = lane >> 4, l16 = lane & 15;
    const int id = blockIdx.x;
    const int xcd = id & 7, jj = id >> 3;          // jj 0..127
    const int bh = xcd * 4 + (jj >> 5), nb = jj & 31;
    const int b = bh >> 3, h = bh & 7;
    const int n0 = nb * 64;                        // 64 q-rows per block
    const int sr0 = hv * 16;                       // staging rows for this wave
    const size_t qkBase = ((size_t)b * NN) * CC + h * DD;
    const size_t vBase  = (((size_t)b * HH + h) * DD) * NN;
    const int r8 = lane >> 3, seg = lane & 7;      // staging: 8 rows x 8x16B per GLD
    const int segp = seg ^ r8;                     // write-side swizzle
    const int lk = l16 & 7;                        // read-side swizzle key

    const u16* kp0 = Kg + qkBase + (size_t)(sr0 + r8) * CC + segp * 8;
    const u16* kp1 = kp0 + (size_t)8 * CC;
    const u16* vp0 = Vg + vBase + (size_t)(sr0 + r8) * NN + segp * 8;
    const u16* vp1 = vp0 + (size_t)8 * NN;

    // Q fragments (loop-invariant), B-operand of 16x16x32: col=n, k=d
    bf16x8 qf[4][2];
#pragma unroll
    for (int qs = 0; qs < 4; ++qs) {
        int n = n0 + qs * 16 + l16;
#pragma unroll
        for (int ks = 0; ks < 2; ++ks)
            qf[qs][ks] = *(const bf16x8*)&Qg[qkBase + (size_t)n * CC + ks * 32 + quad * 8];
    }

    f32x4 oa[4][4] = {};         // [qs][ct]
    float lp[4] = {};            // partial l: per lane covers m = hv*16+quad*4+{0..3}

    // prologue: stage tile 0 into buffer 0 (2 K + 2 V GLD16 per wave)
    GLD16(kp0, Ksb[0] + sr0 * 64);
    GLD16(kp1, Ksb[0] + (sr0 + 8) * 64);
    GLD16(vp0, Vtb[0] + sr0 * 64);
    GLD16(vp1, Vtb[0] + (sr0 + 8) * 64);
    kp0 += 64 * CC; kp1 += 64 * CC; vp0 += 64; vp1 += 64;

#define ATTN_PREF(BUF) do { \
        GLD16(kp0, Ksb[BUF] + sr0 * 64); \
        GLD16(kp1, Ksb[BUF] + (sr0 + 8) * 64); \
        GLD16(vp0, Vtb[BUF] + sr0 * 64); \
        GLD16(vp1, Vtb[BUF] + (sr0 + 8) * 64); \
        kp0 += 64 * CC; kp1 += 64 * CC; vp0 += 64; vp1 += 64; \
    } while (0)

#define ATTN_BODY(CUR) do { \
        const u16* ksb = Ksb[CUR]; \
        const u16* vtb = Vtb[CUR]; \
        /* own K-quarter fragments: rows hv*16+l16, d = ks*32+quad*8 */ \
        bf16x8 ak[2]; \
        _Pragma("unroll") \
        for (int ks = 0; ks < 2; ++ks) \
            ak[ks] = *(const bf16x8*)&ksb[(sr0 + l16) * 64 + ((ks * 4 + quad) ^ lk) * 8]; \
        /* own V-quarter fragments: row d=ct*16+l16, m = hv*16+quad*4+{0..3} */ \
        bf16x4 vb[4]; \
        _Pragma("unroll") \
        for (int ct = 0; ct < 4; ++ct) { \
            int g = (hv * 2 + (quad >> 1)) ^ lk; \
            vb[ct] = *(const bf16x4*)&vtb[(ct * 16 + l16) * 64 + g * 8 + (quad & 1) * 4]; \
        } \
        /* QK + exp2 + pack per qs; p is lane-local for PV */ \
        bf16x4 pa[4]; \
        _Pragma("unroll") \
        for (int qs = 0; qs < 4; ++qs) { \
            f32x4 st = {}; \
            __builtin_amdgcn_s_setprio(1); \
            st = __builtin_amdgcn_mfma_f32_16x16x32_bf16(ak[0], qf[qs][0], st, 0, 0, 0); \
            st = __builtin_amdgcn_mfma_f32_16x16x32_bf16(ak[1], qf[qs][1], st, 0, 0, 0); \
            __builtin_amdgcn_s_setprio(0); \
            float e0 = __ocml_native_exp2_f32(st[0]); \
            float e1 = __ocml_native_exp2_f32(st[1]); \
            float e2 = __ocml_native_exp2_f32(st[2]); \
            float e3 = __ocml_native_exp2_f32(st[3]); \
            lp[qs] += (e0 + e1) + (e2 + e3); \
            uint2 t; \
            t.x = __builtin_amdgcn_perm(__builtin_bit_cast(unsigned, e1), __builtin_bit_cast(unsigned, e0), 0x07060302u); \
            t.y = __builtin_amdgcn_perm(__builtin_bit_cast(unsigned, e3), __builtin_bit_cast(unsigned, e2), 0x07060302u); \
            pa[qs] = __builtin_bit_cast(bf16x4, t); \
        } \
        /* PV over own 16 kv-rows, K=16 MFMA */ \
        __builtin_amdgcn_s_setprio(1); \
        _Pragma("unroll") \
        for (int ct = 0; ct < 4; ++ct) \
            _Pragma("unroll") \
            for (int qs = 0; qs < 4; ++qs) \
                oa[qs][ct] = MFMA16(pa[qs], vb[ct], oa[qs][ct]); \
        __builtin_amdgcn_s_setprio(0); \
    } while (0)

    for (int it = 0; it < NN / 64; it += 2) {
        __syncthreads();          // buf0 staged; all waves done reading buf1
        ATTN_PREF(1);
        ATTN_BODY(0);
        __syncthreads();          // buf1 staged; all waves done reading buf0
        if (it < NN / 64 - 2)
            ATTN_PREF(0);
        ATTN_BODY(1);
    }
#undef ATTN_PREF
#undef ATTN_BODY

    // ---- merge the 4 kv-quarters' partial O and l via LDS tree ----
    __syncthreads();
    float* M = (float*)pool;
    float* SA = M;                 // slot A: 64 lanes x 68 floats
    float* SB = M + 64 * 68;       // slot B
    float* lbuf = M + 2 * 64 * 68; // 64 floats
    const int mb = lane * 68;

    if (hv == 1 || hv == 3) {
        float* S = (hv == 1) ? SA : SB;
#pragma unroll
        for (int qs = 0; qs < 4; ++qs)
#pragma unroll
            for (int ct = 0; ct < 4; ++ct)
                *(f32x4*)&S[mb + (qs * 4 + ct) * 4] = oa[qs][ct];
#pragma unroll
        for (int qs = 0; qs < 4; ++qs) S[mb + 64 + qs] = lp[qs];
    }
    __syncthreads();
    if (hv == 0) {
#pragma unroll
        for (int qs = 0; qs < 4; ++qs) {
#pragma unroll
            for (int ct = 0; ct < 4; ++ct)
                oa[qs][ct] += *(const f32x4*)&SA[mb + (qs * 4 + ct) * 4];
            lp[qs] += SA[mb + 64 + qs];
        }
    } else if (hv == 2) {
#pragma unroll
        for (int qs = 0; qs < 4; ++qs) {
#pragma unroll
            for (int ct = 0; ct < 4; ++ct)
                oa[qs][ct] += *(const f32x4*)&SB[mb + (qs * 4 + ct) * 4];
            lp[qs] += SB[mb + 64 + qs];
        }
    }
    __syncthreads();
    if (hv == 2) {
#pragma unroll
        for (int qs = 0; qs < 4; ++qs) {
#pragma unroll
            for (int ct = 0; ct < 4; ++ct)
                *(f32x4*)&SA[mb + (qs * 4 + ct) * 4] = oa[qs][ct];
            SA[mb + 64 + qs] = lp[qs];
        }
    }
    __syncthreads();
    if (hv == 0) {
#pragma unroll
        for (int qs = 0; qs < 4; ++qs) {
#pragma unroll
            for (int ct = 0; ct < 4; ++ct)
                oa[qs][ct] += *(const f32x4*)&SA[mb + (qs * 4 + ct) * 4];
            lp[qs] += SA[mb + 64 + qs];
            // reduce l over quads (m-subsets) -> full row-sum, same on all lanes
            float l = lp[qs];
            l += __shfl_xor(l, 16); l += __shfl_xor(l, 32);
            if (quad == 0) lbuf[qs * 16 + l16] = l;
        }
        // transpose l via lbuf (same-wave write->read, lgkm-ordered)
#pragma unroll
        for (int qs = 0; qs < 4; ++qs) {
#pragma unroll
            for (int r = 0; r < 4; ++r) {
                float li = 1.f / lbuf[qs * 16 + quad * 4 + r];
                int n = n0 + qs * 16 + quad * 4 + r;
#pragma unroll
                for (int ct = 0; ct < 4; ++ct)
                    Og[qkBase + (size_t)n * CC + ct * 16 + l16] = f2b(oa[qs][ct][r] * li);
            }
        }
    }
}

// ---------------------------------------------------------------------------
// fp32 [B,C,N] -> bf16 [B,N,C] transpose+convert (64x64 tiles via LDS)
// ---------------------------------------------------------------------------
__global__ __launch_bounds__(256) void transpose_cvt(
    const float* __restrict__ X, u16* __restrict__ Y)
{
    __shared__ float T[64][65];
    const int tid = threadIdx.x;
    const int n0 = blockIdx.x * 64, c0 = blockIdx.y * 64, b = blockIdx.z;
    const int rr = tid >> 4, cc4 = tid & 15;
#pragma unroll
    for (int p = 0; p < 4; ++p) {
        int cl = p * 16 + rr;
        float4 v = *(const float4*)&X[((size_t)b * CC + c0 + cl) * NN + n0 + cc4 * 4];
        T[cl][cc4 * 4 + 0] = v.x; T[cl][cc4 * 4 + 1] = v.y;
        T[cl][cc4 * 4 + 2] = v.z; T[cl][cc4 * 4 + 3] = v.w;
    }
    __syncthreads();
#pragma unroll
    for (int p = 0; p < 4; ++p) {
        int nl = p * 16 + rr;
        ushort4 pk;
        pk.x = f2b(T[cc4 * 4 + 0][nl]);
        pk.y = f2b(T[cc4 * 4 + 1][nl]);
        pk.z = f2b(T[cc4 * 4 + 2][nl]);
        pk.w = f2b(T[cc4 * 4 + 3][nl]);
        *(ushort4*)&Y[((size_t)b * NN + n0 + nl) * CC + c0 + cc4 * 4] = pk;
    }
}

// ---------------------------------------------------------------------------
// One-shot weight prep: fp32->bf16 with optional row/col head-permute + scale.
// ---------------------------------------------------------------------------
__global__ __launch_bounds__(256) void prep_weights(
    const float* __restrict__ Wq, const float* __restrict__ Wk,
    const float* __restrict__ Wv, const float* __restrict__ Wm,
    const float* __restrict__ W1, const float* __restrict__ W2,
    u16* oQ, u16* oK, u16* oV, u16* oM, u16* o1, u16* o2)
{
    const float* W; u16* o; int rows, cols, perm; float sc = 1.f;
    switch (blockIdx.z) {
        case 0: W = Wq; o = oQ; rows = 512;  cols = 512;  perm = 1; sc = SCALE; break;
        case 1: W = Wk; o = oK; rows = 512;  cols = 512;  perm = 1; break;
        case 2: W = Wv; o = oV; rows = 512;  cols = 512;  perm = 1; break;
        case 3: W = Wm; o = oM; rows = 512;  cols = 512;  perm = 2; break;
        case 4: W = W1; o = o1; rows = 1024; cols = 1024; perm = 0; break;
        default: W = W2; o = o2; rows = 512; cols = 1024; perm = 0; break;
    }
    int c = blockIdx.x * 256 + threadIdx.x;
    int r = blockIdx.y;
    if (r >= rows || c >= cols) return;
    int sr = r, scol = c;
    if (perm == 1) sr = (r & 63) * 8 + (r >> 6);
    else if (perm == 2) scol = (c & 63) * 8 + (c >> 6);
    o[(size_t)r * cols + c] = f2b(W[(size_t)sr * cols + scol] * sc);
}

__global__ void prep_bias(const float* __restrict__ bq, const float* __restrict__ bk,
                          const float* __restrict__ bv,
                          float* oq, float* ok, float* ov)
{
    int i = blockIdx.x * 256 + threadIdx.x;
    int y = blockIdx.y;
    const float* s = (y == 0) ? bq : (y == 1) ? bk : bv;
    float* o = (y == 0) ? oq : (y == 1) ? ok : ov;
    float v = s[(i & 63) * 8 + (i >> 6)];
    if (y == 0) v *= SCALE;
    o[i] = v;
}

// ---------------------------------------------------------------------------
// Instance-norm apply (+ReLU) on bf16 [B,N,1024], in place. Vectorized
// bf16x8, 256 threads, grid (128 nz, 4 b) = 512 blocks.
// ---------------------------------------------------------------------------
__global__ __launch_bounds__(256) void inorm_p2(
    u16* __restrict__ X, const float* __restrict__ Ssum, const float* __restrict__ Ssq)
{
    const int tid = threadIdx.x;
    const int cidx = (tid & 127) * 8;
    const int rq = tid >> 7;              // 0..1
    const int b = blockIdx.y, nz = blockIdx.x;
    float4 s0 = *(const float4*)&Ssum[b * 1024 + cidx];
    float4 s1 = *(const float4*)&Ssum[b * 1024 + cidx + 4];
    float4 q0 = *(const float4*)&Ssq[b * 1024 + cidx];
    float4 q1 = *(const float4*)&Ssq[b * 1024 + cidx + 4];
    float mean[8] = { s0.x, s0.y, s0.z, s0.w, s1.x, s1.y, s1.z, s1.w };
    float sq[8]   = { q0.x, q0.y, q0.z, q0.w, q1.x, q1.y, q1.z, q1.w };
    float rstd[8];
#pragma unroll
    for (int j = 0; j < 8; ++j) {
        float m = mean[j] * (1.f / NN);
        float v = sq[j] * (1.f / NN) - m * m;
        mean[j] = m; rstd[j] = rsqrtf(fmaxf(v, 0.f) + 1e-5f);
    }
    size_t base = ((size_t)b * NN + nz * 16 + rq * 8) * 1024 + cidx;
    for (int i = 0; i < 8; ++i) {
        bf16x8 v = *(const bf16x8*)&X[base + (size_t)i * 1024];
        bf16x8 o;
#pragma unroll
        for (int j = 0; j < 8; ++j) {
            float x = b2f((u16)v[j]);
            x = (x - mean[j]) * rstd[j];
            o[j] = (short)f2b(fmaxf(x, 0.f));
        }
        *(bf16x8*)&X[base + (size_t)i * 1024] = o;
    }
}

// ---------------------------------------------------------------------------
extern "C" void kernel_launch(void* const* d_in, const int* in_sizes, int n_in,
                              void* d_out, int out_size, void* d_ws, size_t ws_size,
                              hipStream_t stream)
{
    (void)in_sizes; (void)n_in; (void)out_size; (void)ws_size;
    const float* src = (const float*)d_in[0];
    const float* tgt = (const float*)d_in[1];
    const float* Wq = (const float*)d_in[2];  const float* bq = (const float*)d_in[3];
    const float* Wk = (const float*)d_in[4];  const float* bk = (const float*)d_in[5];
    const float* Wv = (const float*)d_in[6];  const float* bv = (const float*)d_in[7];
    const float* Wm = (const float*)d_in[8];  const float* bm = (const float*)d_in[9];
    const float* W1 = (const float*)d_in[10]; const float* b1 = (const float*)d_in[11];
    const float* W2 = (const float*)d_in[12]; const float* b2 = (const float*)d_in[13];

    char* w = (char*)d_ws;
    u16* WQp = (u16*)(w);
    u16* WKp = (u16*)(w + (512u << 10));
    u16* WVp = (u16*)(w + (1u << 20));
    u16* WMp = (u16*)(w + (3u << 19));
    u16* W1b = (u16*)(w + (2u << 20));
    u16* W2b = (u16*)(w + (4u << 20));
    float* BQp = (float*)(w + (5u << 20));
    float* BKp = BQp + 512;
    float* BVp = BQp + 1024;
    float* STS = BQp + 1536;
    float* STQ = STS + 4096;
    u16* X0 = (u16*)(w + ( 6u << 20));        // 8 MB regions
    u16* X1 = (u16*)(w + (14u << 20));
    u16* B0 = (u16*)(w + (22u << 20));
    u16* B1 = (u16*)(w + (30u << 20));
    u16* B2 = (u16*)(w + (38u << 20));
    u16* B3 = (u16*)(w + (46u << 20));

    float* out = (float*)d_out;
    const size_t R = (size_t)BB * CC * NN;
    dim3 blk(256), blkA(512);

    prep_weights<<<dim3(4, 1024, 6), blk, 0, stream>>>(Wq, Wk, Wv, Wm, W1, W2,
                                                       WQp, WKp, WVp, WMp, W1b, W2b);
    prep_bias<<<dim3(2, 3), blk, 0, stream>>>(bq, bk, bv, BQp, BKp, BVp);
    transpose_cvt<<<dim3(32, 8, 4), blk, 0, stream>>>(src, X0);
    transpose_cvt<<<dim3(32, 8, 4), blk, 0, stream>>>(tgt, X1);

    dim3 gQKV(16, 12, 4), gM(16, 8, 4), gW1(16, 8, 4), gW2(16, 8, 4), gIN(128, 4);

    // ---- pipeline 1: q<-src(X0), k/v<-tgt(X1), residual=src ----
    gemm_qkv<<<gQKV, blkA, 0, stream>>>(WQp, BQp, X0, B0, WKp, BKp, B1, WVp, BVp, B2, X1);
    attn<<<dim3(1024), blk, 0, stream>>>(B0, B1, B2, B3);
    gemm_bf16_t<2><<<gM, blk, 0, stream>>>(WMp, bm, B3, nullptr, 512, 512, 512, nullptr, nullptr, B0, 0);
    hipMemsetAsync(STS, 0, 8192 * sizeof(float), stream);
    gemm_w1<<<gW1, blkA, 0, stream>>>(W1b, b1, X0, B0, B1, STS, STQ);
    inorm_p2<<<gIN, blk, 0, stream>>>(B1, STS, STQ);
    gemm_bf16_t<2><<<gW2, blk, 0, stream>>>(W2b, b2, B1, nullptr, 1024, 1024, 512, src, out, B3, 2);

    // ---- pipeline 2: q<-tgt(X1), k/v<-src_new(B3), residual=tgt ----
    gemm_qkv<<<gQKV, blkA, 0, stream>>>(WQp, BQp, X1, X0, WKp, BKp, B0, WVp, BVp, B1, B3);
    attn<<<dim3(1024), blk, 0, stream>>>(X0, B0, B1, B2);
    gemm_bf16_t<2><<<gM, blk, 0, stream>>>(WMp, bm, B2, nullptr, 512, 512, 512, nullptr, nullptr, X0, 0);
    hipMemsetAsync(STS, 0, 8192 * sizeof(float), stream);
    gemm_w1<<<gW1, blkA, 0, stream>>>(W1b, b1, X1, X0, B0, STS, STQ);
    inorm_p2<<<gIN, blk, 0, stream>>>(B0, STS, STQ);
    gemm_bf16_t<2><<<gW2, blk, 0, stream>>>(W2b, b2, B0, nullptr, 1024, 1024, 512, tgt, out + R, nullptr, 3);
}

// Round 11
// 384.494 us; speedup vs baseline: 1.0614x; 1.0614x over previous
//
#include <hip/hip_runtime.h>

#define NN 2048
#define CC 512
#define BB 4
#define HH 8
#define DD 64
#define SCALE 0.18033688011112043f   // 0.125 * log2(e), folded into Wq/bq

typedef unsigned short u16;
typedef __attribute__((ext_vector_type(8))) short bf16x8;   // 8 bf16 (4 VGPRs)
typedef __attribute__((ext_vector_type(4))) float f32x4;    // MFMA accumulator

extern "C" __device__ float __ocml_native_exp2_f32(float);  // bare v_exp_f32

__device__ inline u16 f2b(float x) {           // fp32 -> bf16 (RNE)
    unsigned u = __builtin_bit_cast(unsigned, x);
    u += 0x7fffu + ((u >> 16) & 1u);
    return (u16)(u >> 16);
}
__device__ inline float b2f(u16 h) {
    unsigned u = ((unsigned)h) << 16;
    return __builtin_bit_cast(float, u);
}

#define GLD16(g, l) __builtin_amdgcn_global_load_lds( \
    (const __attribute__((address_space(1))) unsigned int*)(g), \
    (__attribute__((address_space(3))) unsigned int*)(l), 16, 0, 0)

// ---------------------------------------------------------------------------
// 4-wave GEMM core (M / W2 path): 128(n) x (JT*32)(o) x 64(k), dbuf option.
// XOR-swizzled 16B granules — conflict-free ds_read_b128.
// ---------------------------------------------------------------------------
template<int JT, bool DBUF>
__device__ __forceinline__ void gemm_core_t(
    const u16* __restrict__ Xa, const u16* __restrict__ Xb, int Ca, int K,
    const u16* __restrict__ Wt, size_t rowBase,
    u16* As, u16* Bs, f32x4 (&acc)[4][JT])
{
    constexpr int OT = JT * 32;
    constexpr int ASZ = 128 * 64, BSZ = OT * 64;
    const int tid = threadIdx.x;
    const int lane = tid & 63, w = tid >> 6;
    const int quad = lane >> 4, l16 = lane & 15;
    const int wrow = w & 1, wcol = w >> 1;
    const int arow = lane >> 3, aseg = lane & 7;   // 8 rows x 8x16B per GLD set
    const int asw = aseg ^ arow;                   // pre-swizzled source granule
    const int lk = l16 & 7;                        // read-side swizzle key

    auto stage = [&](int k0, u16* Ad, u16* Bd) {
        const u16* Xs; int Crow, cc;
        if (k0 < Ca) { Xs = Xa; Crow = Ca; cc = k0; }
        else         { Xs = Xb; Crow = K - Ca; cc = k0 - Ca; }
#pragma unroll
        for (int i = 0; i < 4; ++i) {
            int rl = w * 32 + i * 8 + arow;
            int la = __builtin_amdgcn_readfirstlane((w * 32 + i * 8) * 64);
            GLD16(Xs + (rowBase + rl) * (size_t)Crow + cc + asw * 8, (char*)Ad + (size_t)la * 2);
        }
#pragma unroll
        for (int i = 0; i < OT / 32; ++i) {
            int rl = w * (OT / 4) + i * 8 + arow;
            int la = __builtin_amdgcn_readfirstlane((w * (OT / 4) + i * 8) * 64);
            GLD16(Wt + (size_t)rl * K + k0 + asw * 8, (char*)Bd + (size_t)la * 2);
        }
    };
    auto compute = [&](const u16* Ac, const u16* Bc) {
#pragma unroll
        for (int kk = 0; kk < 2; ++kk) {
            const int g = ((kk * 4 + quad) ^ lk) * 8;
            bf16x8 av[4], bv[JT];
#pragma unroll
            for (int i = 0; i < 4; ++i)
                av[i] = *(const bf16x8*)&Ac[(wrow * 64 + i * 16 + l16) * 64 + g];
#pragma unroll
            for (int jj = 0; jj < JT; ++jj)
                bv[jj] = *(const bf16x8*)&Bc[(wcol * JT * 16 + jj * 16 + l16) * 64 + g];
#pragma unroll
            for (int i = 0; i < 4; ++i)
#pragma unroll
                for (int jj = 0; jj < JT; ++jj)
                    acc[i][jj] = __builtin_amdgcn_mfma_f32_16x16x32_bf16(av[i], bv[jj], acc[i][jj], 0, 0, 0);
        }
    };

    if constexpr (DBUF) {
        stage(0, As, Bs);
        const int nt = K / 64;
        for (int t = 0; t < nt; ++t) {
            const u16* Ac = As + (t & 1) * ASZ;
            const u16* Bc = Bs + (t & 1) * BSZ;
            __syncthreads();
            if (t + 1 < nt)
                stage((t + 1) * 64, As + ((t + 1) & 1) * ASZ, Bs + ((t + 1) & 1) * BSZ);
            compute(Ac, Bc);
        }
    } else {
        for (int k0 = 0; k0 < K; k0 += 64) {
            stage(k0, As, Bs);
            __syncthreads();
            compute(As, Bs);
            __syncthreads();
        }
    }
}

// mode 0: outB bf16 [B,N,Cout]
// mode 1: outB bf16 [B,H,D,N] (o=(h<<6)|d)
// mode 2: outF fp32 [B,Cout,N]=acc+bias+res AND outB bf16 [B,N,Cout]
// mode 3: outF only
template<int JT>
__device__ __forceinline__ void gemm_epilogue_t(
    f32x4 (&acc)[4][JT], const float* __restrict__ bias, int mode,
    int b, int n0, int o0, int Cout,
    const float* __restrict__ res, float* __restrict__ outF, u16* __restrict__ outB)
{
    const int tid = threadIdx.x;
    const int lane = tid & 63, w = tid >> 6;
    const int quad = lane >> 4, l16 = lane & 15;
    const int wrow = w & 1, wcol = w >> 1;
    const size_t bN = (size_t)b * NN;
    const int nb0 = n0 + wrow * 64, ob0 = o0 + wcol * JT * 16;

    if (mode == 0) {
#pragma unroll
        for (int j = 0; j < JT; ++j) {
            int o = ob0 + j * 16 + l16;
            float bs = bias[o];
#pragma unroll
            for (int i = 0; i < 4; ++i)
#pragma unroll
                for (int r = 0; r < 4; ++r) {
                    int n = nb0 + i * 16 + quad * 4 + r;
                    outB[(bN + n) * Cout + o] = f2b(acc[i][j][r] + bs);
                }
        }
    } else if (mode == 1) {
#pragma unroll
        for (int j = 0; j < JT; ++j) {
            int o = ob0 + j * 16 + l16;
            float bs = bias[o];
            int h = o >> 6, d = o & 63;
#pragma unroll
            for (int i = 0; i < 4; ++i) {
                int n = nb0 + i * 16 + quad * 4;
                ushort4 pk;
                pk.x = f2b(acc[i][j][0] + bs); pk.y = f2b(acc[i][j][1] + bs);
                pk.z = f2b(acc[i][j][2] + bs); pk.w = f2b(acc[i][j][3] + bs);
                *(ushort4*)&outB[(((size_t)b * HH + h) * DD + d) * NN + n] = pk;
            }
        }
    } else {
#pragma unroll
        for (int j = 0; j < JT; ++j) {
            int o = ob0 + j * 16 + l16;
            float bs = bias[o];
#pragma unroll
            for (int i = 0; i < 4; ++i) {
                int n = nb0 + i * 16 + quad * 4;
                size_t ad = ((size_t)b * Cout + o) * NN + n;
                float4 rv = *(const float4*)&res[ad];
                float4 yv;
                yv.x = acc[i][j][0] + bs + rv.x;
                yv.y = acc[i][j][1] + bs + rv.y;
                yv.z = acc[i][j][2] + bs + rv.z;
                yv.w = acc[i][j][3] + bs + rv.w;
                *(float4*)&outF[ad] = yv;
                if (mode == 2) {
                    outB[(bN + n + 0) * Cout + o] = f2b(yv.x);
                    outB[(bN + n + 1) * Cout + o] = f2b(yv.y);
                    outB[(bN + n + 2) * Cout + o] = f2b(yv.z);
                    outB[(bN + n + 3) * Cout + o] = f2b(yv.w);
                }
            }
        }
    }
}

template<int JT>
__global__ __launch_bounds__(256, 3) void gemm_bf16_t(
    const u16* __restrict__ Wb, const float* __restrict__ bias,
    const u16* __restrict__ Xa, const u16* __restrict__ Xb,
    int Ca, int K, int Cout,
    const float* __restrict__ res, float* __restrict__ outF,
    u16* __restrict__ outB, int mode)
{
    __shared__ u16 As[2 * 128 * 64];
    __shared__ u16 Bs[2 * JT * 32 * 64];
    const int b = blockIdx.z, n0 = blockIdx.x * 128, o0 = blockIdx.y * (JT * 32);
    f32x4 acc[4][JT] = {};
    gemm_core_t<JT, true>(Xa, Xb, Ca, K, Wb + (size_t)o0 * K, (size_t)b * NN + n0, As, Bs, acc);
    gemm_epilogue_t<JT>(acc, bias, mode, b, n0, o0, Cout, res, outF, outB);
}

// ---------------------------------------------------------------------------
// 8-wave GEMM core (QKV / W1 path): 128(n) x 128(o) x 64(k) per block.
// ---------------------------------------------------------------------------
template<bool DBUF>
__device__ __forceinline__ void gemm_core8(
    const u16* __restrict__ Xa, const u16* __restrict__ Xb, int Ca, int K,
    const u16* __restrict__ Wt, size_t rowBase,
    u16* As, u16* Bs, f32x4 (&acc)[4][2])
{
    constexpr int ASZ = 128 * 64, BSZ = 128 * 64;
    const int tid = threadIdx.x;
    const int lane = tid & 63, w = tid >> 6;
    const int quad = lane >> 4, l16 = lane & 15;
    const int wr = w & 1, wc = w >> 1;
    const int arow = lane >> 3, aseg = lane & 7;
    const int asw = aseg ^ arow;
    const int lk = l16 & 7;

    auto stage = [&](int k0, u16* Ad, u16* Bd) {
        const u16* Xs; int Crow, cc;
        if (k0 < Ca) { Xs = Xa; Crow = Ca; cc = k0; }
        else         { Xs = Xb; Crow = K - Ca; cc = k0 - Ca; }
#pragma unroll
        for (int i = 0; i < 2; ++i) {
            int rl = w * 16 + i * 8 + arow;
            int la = __builtin_amdgcn_readfirstlane((w * 16 + i * 8) * 64);
            GLD16(Xs + (rowBase + rl) * (size_t)Crow + cc + asw * 8, (char*)Ad + (size_t)la * 2);
            GLD16(Wt + (size_t)rl * K + k0 + asw * 8, (char*)Bd + (size_t)la * 2);
        }
    };
    auto compute = [&](const u16* Ac, const u16* Bc) {
#pragma unroll
        for (int kk = 0; kk < 2; ++kk) {
            const int g = ((kk * 4 + quad) ^ lk) * 8;
            bf16x8 av[4], bv[2];
#pragma unroll
            for (int i = 0; i < 4; ++i)
                av[i] = *(const bf16x8*)&Ac[(wr * 64 + i * 16 + l16) * 64 + g];
#pragma unroll
            for (int j = 0; j < 2; ++j)
                bv[j] = *(const bf16x8*)&Bc[(wc * 32 + j * 16 + l16) * 64 + g];
#pragma unroll
            for (int i = 0; i < 4; ++i)
#pragma unroll
                for (int j = 0; j < 2; ++j)
                    acc[i][j] = __builtin_amdgcn_mfma_f32_16x16x32_bf16(av[i], bv[j], acc[i][j], 0, 0, 0);
        }
    };

    if constexpr (DBUF) {
        stage(0, As, Bs);
        const int nt = K / 64;
        for (int t = 0; t < nt; ++t) {
            const u16* Ac = As + (t & 1) * ASZ;
            const u16* Bc = Bs + (t & 1) * BSZ;
            __syncthreads();
            if (t + 1 < nt)
                stage((t + 1) * 64, As + ((t + 1) & 1) * ASZ, Bs + ((t + 1) & 1) * BSZ);
            compute(Ac, Bc);
        }
    } else {
        for (int k0 = 0; k0 < K; k0 += 64) {
            stage(k0, As, Bs);
            __syncthreads();
            compute(As, Bs);
            __syncthreads();
        }
    }
}

// modes 0/1 (QKV path)
__device__ __forceinline__ void gemm_epilogue8(
    f32x4 (&acc)[4][2], const float* __restrict__ bias, int mode,
    int b, int n0, int o0, int Cout, u16* __restrict__ outB)
{
    const int tid = threadIdx.x;
    const int lane = tid & 63, w = tid >> 6;
    const int quad = lane >> 4, l16 = lane & 15;
    const int wr = w & 1, wc = w >> 1;
    const size_t bN = (size_t)b * NN;
    const int nb0 = n0 + wr * 64, ob0 = o0 + wc * 32;

    if (mode == 0) {
#pragma unroll
        for (int j = 0; j < 2; ++j) {
            int o = ob0 + j * 16 + l16;
            float bs = bias[o];
#pragma unroll
            for (int i = 0; i < 4; ++i)
#pragma unroll
                for (int r = 0; r < 4; ++r) {
                    int n = nb0 + i * 16 + quad * 4 + r;
                    outB[(bN + n) * Cout + o] = f2b(acc[i][j][r] + bs);
                }
        }
    } else {
#pragma unroll
        for (int j = 0; j < 2; ++j) {
            int o = ob0 + j * 16 + l16;
            float bs = bias[o];
            int h = o >> 6, d = o & 63;
#pragma unroll
            for (int i = 0; i < 4; ++i) {
                int n = nb0 + i * 16 + quad * 4;
                ushort4 pk;
                pk.x = f2b(acc[i][j][0] + bs); pk.y = f2b(acc[i][j][1] + bs);
                pk.z = f2b(acc[i][j][2] + bs); pk.w = f2b(acc[i][j][3] + bs);
                *(ushort4*)&outB[(((size_t)b * HH + h) * DD + d) * NN + n] = pk;
            }
        }
    }
}

// Fused Q+K+V, 8-wave dbuf: yb<4 -> Q from XQ; 4..7 -> K from XKV; 8..11 -> V.
__global__ __launch_bounds__(512, 4) void gemm_qkv(
    const u16* __restrict__ WQ, const float* __restrict__ bQ,
    const u16* __restrict__ XQ, u16* __restrict__ outQ,
    const u16* __restrict__ WK, const float* __restrict__ bK, u16* __restrict__ outK,
    const u16* __restrict__ WV, const float* __restrict__ bV, u16* __restrict__ outV,
    const u16* __restrict__ XKV)
{
    __shared__ u16 As[2 * 128 * 64];
    __shared__ u16 Bs[2 * 128 * 64];
    const int yb = blockIdx.y;
    const u16* W; const float* bias; const u16* X; u16* outB; int mode, o0;
    if (yb < 4)      { o0 = yb * 128;       W = WQ; bias = bQ; X = XQ;  outB = outQ; mode = 0; }
    else if (yb < 8) { o0 = (yb - 4) * 128; W = WK; bias = bK; X = XKV; outB = outK; mode = 0; }
    else             { o0 = (yb - 8) * 128; W = WV; bias = bV; X = XKV; outB = outV; mode = 1; }
    const int b = blockIdx.z, n0 = blockIdx.x * 128;
    f32x4 acc[4][2] = {};
    gemm_core8<true>(X, nullptr, 512, 512, W + (size_t)o0 * 512, (size_t)b * NN + n0, As, Bs, acc);
    gemm_epilogue8(acc, bias, mode, b, n0, o0, 512, outB);
}

// W1 GEMM, 8-wave dbuf, instance-norm statistics fused into the epilogue.
__global__ __launch_bounds__(512, 4) void gemm_w1(
    const u16* __restrict__ Wb, const float* __restrict__ bias,
    const u16* __restrict__ Xa, const u16* __restrict__ Xb,
    u16* __restrict__ outB, float* __restrict__ Ssum, float* __restrict__ Ssq)
{
    __shared__ u16 As[2 * 128 * 64];
    __shared__ u16 Bs[2 * 128 * 64];
    const int b = blockIdx.z, n0 = blockIdx.x * 128, o0 = blockIdx.y * 128;
    f32x4 acc[4][2] = {};
    gemm_core8<true>(Xa, Xb, 512, 1024, Wb + (size_t)o0 * 1024, (size_t)b * NN + n0, As, Bs, acc);

    const int tid = threadIdx.x;
    const int lane = tid & 63, w = tid >> 6;
    const int quad = lane >> 4, l16 = lane & 15;
    const int wr = w & 1, wc = w >> 1;
    const size_t bN = (size_t)b * NN;
    const int nb0 = n0 + wr * 64, ob0 = o0 + wc * 32;

#pragma unroll
    for (int j = 0; j < 2; ++j) {
        int o = ob0 + j * 16 + l16;
        float bs = bias[o];
        float s = 0.f, q = 0.f;
#pragma unroll
        for (int i = 0; i < 4; ++i)
#pragma unroll
            for (int r = 0; r < 4; ++r) {
                int n = nb0 + i * 16 + quad * 4 + r;
                float y = acc[i][j][r] + bs;
                s += y; q += y * y;
                outB[(bN + n) * 1024 + o] = f2b(y);
            }
        s += __shfl_xor(s, 16); s += __shfl_xor(s, 32);   // sum over quad -> 64 rows
        q += __shfl_xor(q, 16); q += __shfl_xor(q, 32);
        if (quad == 0) {
            atomicAdd(&Ssum[b * 1024 + o], s);
            atomicAdd(&Ssq[b * 1024 + o], q);
        }
    }
}

// ---------------------------------------------------------------------------
// Flash attention, MFMA, no max-shift (scores O(1), softmax shift-invariant).
// Q pre-scaled by 0.125*log2e at weight-prep -> p = exp2(s) directly.
// R11 = R9 attn revert (stable 44.0 us; R10's P-in-register kv-split-4
// traded the DS win for 2x PV MFMA issue + occupancy loss, 58.9 us).
// 8 waves = 4 q-groups x 2 kv-halves; K/V double-buffered via
// global_load_lds, XOR-swizzled 16B granules; prefetch right after each
// barrier. Merge stride 44 floats. Grid 512 XCD-swizzled (4 heads/XCD).
// ---------------------------------------------------------------------------
__global__ __launch_bounds__(512, 4) void attn(
    const u16* __restrict__ Qg, const u16* __restrict__ Kg,
    const u16* __restrict__ Vg, u16* __restrict__ Og)
{
    __shared__ __align__(16) u16 pool[6 * 4096];   // Ks0|Ks1|Vt0|Vt1|Ps(128x64) = 48KB
    u16* const Ksb[2] = { pool, pool + 4096 };
    u16* const Vtb[2] = { pool + 2 * 4096, pool + 3 * 4096 };
    u16* const Ps = pool + 4 * 4096;
    const int tid = threadIdx.x;
    const int lane = tid & 63, w = tid >> 6;       // 8 waves
    const int qg = w & 3, hv = w >> 2;             // q-group, kv-half
    const int quad = lane >> 4, l16 = lane & 15;
    const int id = blockIdx.x;
    const int xcd = id & 7, jj = id >> 3;          // jj 0..63
    const int bh = xcd * 4 + (jj >> 4), nb = jj & 15;
    const int b = bh >> 3, h = bh & 7;
    const int n0 = nb * 128, wn0 = qg * 32;        // 32 q-cols per wave
    const int sr0 = w * 8;                         // staging rows for this wave
    const size_t qkBase = ((size_t)b * NN) * CC + h * DD;
    const size_t vBase  = (((size_t)b * HH + h) * DD) * NN;
    const int r8 = lane >> 3, seg = lane & 7;      // staging: 8 rows x 8x16B per wave
    const int segp = seg ^ r8;                     // write-side swizzle
    const int lk = l16 & 7;                        // read-side swizzle key

    const u16* kp = Kg + qkBase + (size_t)(sr0 + r8) * CC + segp * 8;
    const u16* vp = Vg + vBase + (size_t)(sr0 + r8) * NN + segp * 8;

    bf16x8 qf[2][2];
#pragma unroll
    for (int qs = 0; qs < 2; ++qs) {
        int n = n0 + wn0 + qs * 16 + l16;
#pragma unroll
        for (int ks = 0; ks < 2; ++ks)
            qf[qs][ks] = *(const bf16x8*)&Qg[qkBase + (size_t)n * CC + ks * 32 + quad * 8];
    }

    const short oneb = 0x3F80;
    const bf16x8 ones = {oneb, oneb, oneb, oneb, oneb, oneb, oneb, oneb};
    f32x4 oa[2][4] = {};
    f32x4 lacc[2] = {};

    GLD16(kp, Ksb[0] + sr0 * 64);
    GLD16(vp, Vtb[0] + sr0 * 64);
    kp += 64 * CC; vp += 64;

#define ATTN_PREF(BUF) do { \
        GLD16(kp, Ksb[BUF] + sr0 * 64); \
        GLD16(vp, Vtb[BUF] + sr0 * 64); \
        kp += 64 * CC; vp += 64; \
    } while (0)

#define ATTN_BODY(CUR) do { \
        const u16* ksb = Ksb[CUR]; \
        const u16* vtb = Vtb[CUR]; \
        f32x4 st[2][2] = {}; \
        _Pragma("unroll") \
        for (int ks = 0; ks < 2; ++ks) { \
            bf16x8 ak[2]; \
            _Pragma("unroll") \
            for (int rtl = 0; rtl < 2; ++rtl) \
                ak[rtl] = *(const bf16x8*)&ksb[(hv * 32 + rtl * 16 + l16) * 64 + ((ks * 4 + quad) ^ lk) * 8]; \
            __builtin_amdgcn_s_setprio(1); \
            _Pragma("unroll") \
            for (int rtl = 0; rtl < 2; ++rtl) \
                _Pragma("unroll") \
                for (int qs = 0; qs < 2; ++qs) \
                    st[qs][rtl] = __builtin_amdgcn_mfma_f32_16x16x32_bf16(ak[rtl], qf[qs][ks], st[qs][rtl], 0, 0, 0); \
            __builtin_amdgcn_s_setprio(0); \
        } \
        _Pragma("unroll") \
        for (int qs = 0; qs < 2; ++qs) { \
            int nrow = wn0 + qs * 16 + l16; \
            _Pragma("unroll") \
            for (int rtl = 0; rtl < 2; ++rtl) { \
                unsigned u0 = __builtin_bit_cast(unsigned, __ocml_native_exp2_f32(st[qs][rtl][0])); \
                unsigned u1 = __builtin_bit_cast(unsigned, __ocml_native_exp2_f32(st[qs][rtl][1])); \
                unsigned u2 = __builtin_bit_cast(unsigned, __ocml_native_exp2_f32(st[qs][rtl][2])); \
                unsigned u3 = __builtin_bit_cast(unsigned, __ocml_native_exp2_f32(st[qs][rtl][3])); \
                uint2 t; \
                t.x = __builtin_amdgcn_perm(u1, u0, 0x07060302u); \
                t.y = __builtin_amdgcn_perm(u3, u2, 0x07060302u); \
                int g = (((hv * 2 + rtl) * 2 + (quad >> 1))) ^ lk; \
                *(uint2*)&Ps[nrow * 64 + g * 8 + (quad & 1) * 4] = t; \
            } \
        } \
        { \
            bf16x8 pa[2]; \
            _Pragma("unroll") \
            for (int qs = 0; qs < 2; ++qs) \
                pa[qs] = *(const bf16x8*)&Ps[(wn0 + qs * 16 + l16) * 64 + ((hv * 4 + quad) ^ lk) * 8]; \
            bf16x8 vb[4]; \
            _Pragma("unroll") \
            for (int ct = 0; ct < 4; ++ct) \
                vb[ct] = *(const bf16x8*)&vtb[(ct * 16 + l16) * 64 + ((hv * 4 + quad) ^ lk) * 8]; \
            __builtin_amdgcn_s_setprio(1); \
            _Pragma("unroll") \
            for (int ct = 0; ct < 4; ++ct) \
                _Pragma("unroll") \
                for (int qs = 0; qs < 2; ++qs) \
                    oa[qs][ct] = __builtin_amdgcn_mfma_f32_16x16x32_bf16(pa[qs], vb[ct], oa[qs][ct], 0, 0, 0); \
            _Pragma("unroll") \
            for (int qs = 0; qs < 2; ++qs) \
                lacc[qs] = __builtin_amdgcn_mfma_f32_16x16x32_bf16(pa[qs], ones, lacc[qs], 0, 0, 0); \
            __builtin_amdgcn_s_setprio(0); \
        } \
    } while (0)

    for (int it = 0; it < NN / 64; it += 2) {
        __syncthreads();
        ATTN_PREF(1);
        ATTN_BODY(0);
        __syncthreads();
        if (it < NN / 64 - 2)
            ATTN_PREF(0);
        ATTN_BODY(1);
    }
#undef ATTN_PREF
#undef ATTN_BODY

    // merge the two kv-halves' partial O and l via LDS (pool is dead now)
    __syncthreads();
    float* M = (float*)pool;                       // stride 44 floats: 16B-aligned, ~2-way
    const int mbase = (qg * 64 + lane) * 44;
    if (hv == 1) {
#pragma unroll
        for (int qs = 0; qs < 2; ++qs)
#pragma unroll
            for (int ct = 0; ct < 4; ++ct)
                *(f32x4*)&M[mbase + (qs * 4 + ct) * 4] = oa[qs][ct];
        *(f32x4*)&M[mbase + 32] = lacc[0];
        *(f32x4*)&M[mbase + 36] = lacc[1];
    }
    __syncthreads();
    if (hv == 0) {
#pragma unroll
        for (int qs = 0; qs < 2; ++qs)
#pragma unroll
            for (int ct = 0; ct < 4; ++ct)
                oa[qs][ct] += *(const f32x4*)&M[mbase + (qs * 4 + ct) * 4];
        lacc[0] += *(const f32x4*)&M[mbase + 32];
        lacc[1] += *(const f32x4*)&M[mbase + 36];
#pragma unroll
        for (int qs = 0; qs < 2; ++qs)
#pragma unroll
            for (int r = 0; r < 4; ++r) {
                float li = 1.f / lacc[qs][r];
                int n = n0 + wn0 + qs * 16 + quad * 4 + r;
#pragma unroll
                for (int ct = 0; ct < 4; ++ct)
                    Og[qkBase + (size_t)n * CC + ct * 16 + l16] = f2b(oa[qs][ct][r] * li);
            }
    }
}

// ---------------------------------------------------------------------------
// fp32 [B,C,N] -> bf16 [B,N,C] transpose+convert (64x64 tiles via LDS)
// ---------------------------------------------------------------------------
__global__ __launch_bounds__(256) void transpose_cvt(
    const float* __restrict__ X, u16* __restrict__ Y)
{
    __shared__ float T[64][65];
    const int tid = threadIdx.x;
    const int n0 = blockIdx.x * 64, c0 = blockIdx.y * 64, b = blockIdx.z;
    const int rr = tid >> 4, cc4 = tid & 15;
#pragma unroll
    for (int p = 0; p < 4; ++p) {
        int cl = p * 16 + rr;
        float4 v = *(const float4*)&X[((size_t)b * CC + c0 + cl) * NN + n0 + cc4 * 4];
        T[cl][cc4 * 4 + 0] = v.x; T[cl][cc4 * 4 + 1] = v.y;
        T[cl][cc4 * 4 + 2] = v.z; T[cl][cc4 * 4 + 3] = v.w;
    }
    __syncthreads();
#pragma unroll
    for (int p = 0; p < 4; ++p) {
        int nl = p * 16 + rr;
        ushort4 pk;
        pk.x = f2b(T[cc4 * 4 + 0][nl]);
        pk.y = f2b(T[cc4 * 4 + 1][nl]);
        pk.z = f2b(T[cc4 * 4 + 2][nl]);
        pk.w = f2b(T[cc4 * 4 + 3][nl]);
        *(ushort4*)&Y[((size_t)b * NN + n0 + nl) * CC + c0 + cc4 * 4] = pk;
    }
}

// ---------------------------------------------------------------------------
// One-shot weight prep: fp32->bf16 with optional row/col head-permute + scale.
// ---------------------------------------------------------------------------
__global__ __launch_bounds__(256) void prep_weights(
    const float* __restrict__ Wq, const float* __restrict__ Wk,
    const float* __restrict__ Wv, const float* __restrict__ Wm,
    const float* __restrict__ W1, const float* __restrict__ W2,
    u16* oQ, u16* oK, u16* oV, u16* oM, u16* o1, u16* o2)
{
    const float* W; u16* o; int rows, cols, perm; float sc = 1.f;
    switch (blockIdx.z) {
        case 0: W = Wq; o = oQ; rows = 512;  cols = 512;  perm = 1; sc = SCALE; break;
        case 1: W = Wk; o = oK; rows = 512;  cols = 512;  perm = 1; break;
        case 2: W = Wv; o = oV; rows = 512;  cols = 512;  perm = 1; break;
        case 3: W = Wm; o = oM; rows = 512;  cols = 512;  perm = 2; break;
        case 4: W = W1; o = o1; rows = 1024; cols = 1024; perm = 0; break;
        default: W = W2; o = o2; rows = 512; cols = 1024; perm = 0; break;
    }
    int c = blockIdx.x * 256 + threadIdx.x;
    int r = blockIdx.y;
    if (r >= rows || c >= cols) return;
    int sr = r, scol = c;
    if (perm == 1) sr = (r & 63) * 8 + (r >> 6);
    else if (perm == 2) scol = (c & 63) * 8 + (c >> 6);
    o[(size_t)r * cols + c] = f2b(W[(size_t)sr * cols + scol] * sc);
}

__global__ void prep_bias(const float* __restrict__ bq, const float* __restrict__ bk,
                          const float* __restrict__ bv,
                          float* oq, float* ok, float* ov)
{
    int i = blockIdx.x * 256 + threadIdx.x;
    int y = blockIdx.y;
    const float* s = (y == 0) ? bq : (y == 1) ? bk : bv;
    float* o = (y == 0) ? oq : (y == 1) ? ok : ov;
    float v = s[(i & 63) * 8 + (i >> 6)];
    if (y == 0) v *= SCALE;
    o[i] = v;
}

// ---------------------------------------------------------------------------
// Instance-norm apply (+ReLU) on bf16 [B,N,1024], in place. Vectorized
// bf16x8, 256 threads, grid (128 nz, 4 b) = 512 blocks.
// ---------------------------------------------------------------------------
__global__ __launch_bounds__(256) void inorm_p2(
    u16* __restrict__ X, const float* __restrict__ Ssum, const float* __restrict__ Ssq)
{
    const int tid = threadIdx.x;
    const int cidx = (tid & 127) * 8;
    const int rq = tid >> 7;              // 0..1
    const int b = blockIdx.y, nz = blockIdx.x;
    float4 s0 = *(const float4*)&Ssum[b * 1024 + cidx];
    float4 s1 = *(const float4*)&Ssum[b * 1024 + cidx + 4];
    float4 q0 = *(const float4*)&Ssq[b * 1024 + cidx];
    float4 q1 = *(const float4*)&Ssq[b * 1024 + cidx + 4];
    float mean[8] = { s0.x, s0.y, s0.z, s0.w, s1.x, s1.y, s1.z, s1.w };
    float sq[8]   = { q0.x, q0.y, q0.z, q0.w, q1.x, q1.y, q1.z, q1.w };
    float rstd[8];
#pragma unroll
    for (int j = 0; j < 8; ++j) {
        float m = mean[j] * (1.f / NN);
        float v = sq[j] * (1.f / NN) - m * m;
        mean[j] = m; rstd[j] = rsqrtf(fmaxf(v, 0.f) + 1e-5f);
    }
    size_t base = ((size_t)b * NN + nz * 16 + rq * 8) * 1024 + cidx;
    for (int i = 0; i < 8; ++i) {
        bf16x8 v = *(const bf16x8*)&X[base + (size_t)i * 1024];
        bf16x8 o;
#pragma unroll
        for (int j = 0; j < 8; ++j) {
            float x = b2f((u16)v[j]);
            x = (x - mean[j]) * rstd[j];
            o[j] = (short)f2b(fmaxf(x, 0.f));
        }
        *(bf16x8*)&X[base + (size_t)i * 1024] = o;
    }
}

// ---------------------------------------------------------------------------
extern "C" void kernel_launch(void* const* d_in, const int* in_sizes, int n_in,
                              void* d_out, int out_size, void* d_ws, size_t ws_size,
                              hipStream_t stream)
{
    (void)in_sizes; (void)n_in; (void)out_size; (void)ws_size;
    const float* src = (const float*)d_in[0];
    const float* tgt = (const float*)d_in[1];
    const float* Wq = (const float*)d_in[2];  const float* bq = (const float*)d_in[3];
    const float* Wk = (const float*)d_in[4];  const float* bk = (const float*)d_in[5];
    const float* Wv = (const float*)d_in[6];  const float* bv = (const float*)d_in[7];
    const float* Wm = (const float*)d_in[8];  const float* bm = (const float*)d_in[9];
    const float* W1 = (const float*)d_in[10]; const float* b1 = (const float*)d_in[11];
    const float* W2 = (const float*)d_in[12]; const float* b2 = (const float*)d_in[13];

    char* w = (char*)d_ws;
    u16* WQp = (u16*)(w);
    u16* WKp = (u16*)(w + (512u << 10));
    u16* WVp = (u16*)(w + (1u << 20));
    u16* WMp = (u16*)(w + (3u << 19));
    u16* W1b = (u16*)(w + (2u << 20));
    u16* W2b = (u16*)(w + (4u << 20));
    float* BQp = (float*)(w + (5u << 20));
    float* BKp = BQp + 512;
    float* BVp = BQp + 1024;
    float* STS = BQp + 1536;
    float* STQ = STS + 4096;
    u16* X0 = (u16*)(w + ( 6u << 20));        // 8 MB regions
    u16* X1 = (u16*)(w + (14u << 20));
    u16* B0 = (u16*)(w + (22u << 20));
    u16* B1 = (u16*)(w + (30u << 20));
    u16* B2 = (u16*)(w + (38u << 20));
    u16* B3 = (u16*)(w + (46u << 20));

    float* out = (float*)d_out;
    const size_t R = (size_t)BB * CC * NN;
    dim3 blk(256), blkA(512);

    prep_weights<<<dim3(4, 1024, 6), blk, 0, stream>>>(Wq, Wk, Wv, Wm, W1, W2,
                                                       WQp, WKp, WVp, WMp, W1b, W2b);
    prep_bias<<<dim3(2, 3), blk, 0, stream>>>(bq, bk, bv, BQp, BKp, BVp);
    transpose_cvt<<<dim3(32, 8, 4), blk, 0, stream>>>(src, X0);
    transpose_cvt<<<dim3(32, 8, 4), blk, 0, stream>>>(tgt, X1);

    dim3 gQKV(16, 12, 4), gM(16, 8, 4), gW1(16, 8, 4), gW2(16, 8, 4), gIN(128, 4);

    // ---- pipeline 1: q<-src(X0), k/v<-tgt(X1), residual=src ----
    gemm_qkv<<<gQKV, blkA, 0, stream>>>(WQp, BQp, X0, B0, WKp, BKp, B1, WVp, BVp, B2, X1);
    attn<<<dim3(512), blkA, 0, stream>>>(B0, B1, B2, B3);
    gemm_bf16_t<2><<<gM, blk, 0, stream>>>(WMp, bm, B3, nullptr, 512, 512, 512, nullptr, nullptr, B0, 0);
    hipMemsetAsync(STS, 0, 8192 * sizeof(float), stream);
    gemm_w1<<<gW1, blkA, 0, stream>>>(W1b, b1, X0, B0, B1, STS, STQ);
    inorm_p2<<<gIN, blk, 0, stream>>>(B1, STS, STQ);
    gemm_bf16_t<2><<<gW2, blk, 0, stream>>>(W2b, b2, B1, nullptr, 1024, 1024, 512, src, out, B3, 2);

    // ---- pipeline 2: q<-tgt(X1), k/v<-src_new(B3), residual=tgt ----
    gemm_qkv<<<gQKV, blkA, 0, stream>>>(WQp, BQp, X1, X0, WKp, BKp, B0, WVp, BVp, B1, B3);
    attn<<<dim3(512), blkA, 0, stream>>>(X0, B0, B1, B2);
    gemm_bf16_t<2><<<gM, blk, 0, stream>>>(WMp, bm, B2, nullptr, 512, 512, 512, nullptr, nullptr, X0, 0);
    hipMemsetAsync(STS, 0, 8192 * sizeof(float), stream);
    gemm_w1<<<gW1, blkA, 0, stream>>>(W1b, b1, X1, X0, B0, STS, STQ);
    inorm_p2<<<gIN, blk, 0, stream>>>(B0, STS, STQ);
    gemm_bf16_t<2><<<gW2, blk, 0, stream>>>(W2b, b2, B0, nullptr, 1024, 1024, 512, tgt, out + R, nullptr, 3);
}

// Round 12
// 369.044 us; speedup vs baseline: 1.1058x; 1.0419x over previous
//
#include <hip/hip_runtime.h>

#define NN 2048
#define CC 512
#define BB 4
#define HH 8
#define DD 64
#define SCALE 0.18033688011112043f   // 0.125 * log2(e), folded into Wq/bq

typedef unsigned short u16;
typedef __attribute__((ext_vector_type(8))) short bf16x8;   // 8 bf16 (4 VGPRs)
typedef __attribute__((ext_vector_type(4))) float f32x4;    // MFMA accumulator

extern "C" __device__ float __ocml_native_exp2_f32(float);  // bare v_exp_f32

__device__ inline u16 f2b(float x) {           // fp32 -> bf16 (RNE)
    unsigned u = __builtin_bit_cast(unsigned, x);
    u += 0x7fffu + ((u >> 16) & 1u);
    return (u16)(u >> 16);
}
__device__ inline float b2f(u16 h) {
    unsigned u = ((unsigned)h) << 16;
    return __builtin_bit_cast(float, u);
}

#define GLD16(g, l) __builtin_amdgcn_global_load_lds( \
    (const __attribute__((address_space(1))) unsigned int*)(g), \
    (__attribute__((address_space(3))) unsigned int*)(l), 16, 0, 0)

// ---------------------------------------------------------------------------
// 4-wave GEMM core (M / W2 path): 128(n) x (JT*32)(o) x 64(k), dbuf option.
// XOR-swizzled 16B granules — conflict-free ds_read_b128.
// ---------------------------------------------------------------------------
template<int JT, bool DBUF>
__device__ __forceinline__ void gemm_core_t(
    const u16* __restrict__ Xa, const u16* __restrict__ Xb, int Ca, int K,
    const u16* __restrict__ Wt, size_t rowBase,
    u16* As, u16* Bs, f32x4 (&acc)[4][JT])
{
    constexpr int OT = JT * 32;
    constexpr int ASZ = 128 * 64, BSZ = OT * 64;
    const int tid = threadIdx.x;
    const int lane = tid & 63, w = tid >> 6;
    const int quad = lane >> 4, l16 = lane & 15;
    const int wrow = w & 1, wcol = w >> 1;
    const int arow = lane >> 3, aseg = lane & 7;   // 8 rows x 8x16B per GLD set
    const int asw = aseg ^ arow;                   // pre-swizzled source granule
    const int lk = l16 & 7;                        // read-side swizzle key

    auto stage = [&](int k0, u16* Ad, u16* Bd) {
        const u16* Xs; int Crow, cc;
        if (k0 < Ca) { Xs = Xa; Crow = Ca; cc = k0; }
        else         { Xs = Xb; Crow = K - Ca; cc = k0 - Ca; }
#pragma unroll
        for (int i = 0; i < 4; ++i) {
            int rl = w * 32 + i * 8 + arow;
            int la = __builtin_amdgcn_readfirstlane((w * 32 + i * 8) * 64);
            GLD16(Xs + (rowBase + rl) * (size_t)Crow + cc + asw * 8, (char*)Ad + (size_t)la * 2);
        }
#pragma unroll
        for (int i = 0; i < OT / 32; ++i) {
            int rl = w * (OT / 4) + i * 8 + arow;
            int la = __builtin_amdgcn_readfirstlane((w * (OT / 4) + i * 8) * 64);
            GLD16(Wt + (size_t)rl * K + k0 + asw * 8, (char*)Bd + (size_t)la * 2);
        }
    };
    auto compute = [&](const u16* Ac, const u16* Bc) {
#pragma unroll
        for (int kk = 0; kk < 2; ++kk) {
            const int g = ((kk * 4 + quad) ^ lk) * 8;
            bf16x8 av[4], bv[JT];
#pragma unroll
            for (int i = 0; i < 4; ++i)
                av[i] = *(const bf16x8*)&Ac[(wrow * 64 + i * 16 + l16) * 64 + g];
#pragma unroll
            for (int jj = 0; jj < JT; ++jj)
                bv[jj] = *(const bf16x8*)&Bc[(wcol * JT * 16 + jj * 16 + l16) * 64 + g];
#pragma unroll
            for (int i = 0; i < 4; ++i)
#pragma unroll
                for (int jj = 0; jj < JT; ++jj)
                    acc[i][jj] = __builtin_amdgcn_mfma_f32_16x16x32_bf16(av[i], bv[jj], acc[i][jj], 0, 0, 0);
        }
    };

    if constexpr (DBUF) {
        stage(0, As, Bs);
        const int nt = K / 64;
        for (int t = 0; t < nt; ++t) {
            const u16* Ac = As + (t & 1) * ASZ;
            const u16* Bc = Bs + (t & 1) * BSZ;
            __syncthreads();
            if (t + 1 < nt)
                stage((t + 1) * 64, As + ((t + 1) & 1) * ASZ, Bs + ((t + 1) & 1) * BSZ);
            compute(Ac, Bc);
        }
    } else {
        for (int k0 = 0; k0 < K; k0 += 64) {
            stage(k0, As, Bs);
            __syncthreads();
            compute(As, Bs);
            __syncthreads();
        }
    }
}

// mode 0: outB bf16 [B,N,Cout]
// mode 1: outB bf16 [B,H,D,N] (o=(h<<6)|d)
// mode 2: outF fp32 [B,Cout,N]=acc+bias+res AND outB bf16 [B,N,Cout]
// mode 3: outF only
template<int JT>
__device__ __forceinline__ void gemm_epilogue_t(
    f32x4 (&acc)[4][JT], const float* __restrict__ bias, int mode,
    int b, int n0, int o0, int Cout,
    const float* __restrict__ res, float* __restrict__ outF, u16* __restrict__ outB)
{
    const int tid = threadIdx.x;
    const int lane = tid & 63, w = tid >> 6;
    const int quad = lane >> 4, l16 = lane & 15;
    const int wrow = w & 1, wcol = w >> 1;
    const size_t bN = (size_t)b * NN;
    const int nb0 = n0 + wrow * 64, ob0 = o0 + wcol * JT * 16;

    if (mode == 0) {
#pragma unroll
        for (int j = 0; j < JT; ++j) {
            int o = ob0 + j * 16 + l16;
            float bs = bias[o];
#pragma unroll
            for (int i = 0; i < 4; ++i)
#pragma unroll
                for (int r = 0; r < 4; ++r) {
                    int n = nb0 + i * 16 + quad * 4 + r;
                    outB[(bN + n) * Cout + o] = f2b(acc[i][j][r] + bs);
                }
        }
    } else if (mode == 1) {
#pragma unroll
        for (int j = 0; j < JT; ++j) {
            int o = ob0 + j * 16 + l16;
            float bs = bias[o];
            int h = o >> 6, d = o & 63;
#pragma unroll
            for (int i = 0; i < 4; ++i) {
                int n = nb0 + i * 16 + quad * 4;
                ushort4 pk;
                pk.x = f2b(acc[i][j][0] + bs); pk.y = f2b(acc[i][j][1] + bs);
                pk.z = f2b(acc[i][j][2] + bs); pk.w = f2b(acc[i][j][3] + bs);
                *(ushort4*)&outB[(((size_t)b * HH + h) * DD + d) * NN + n] = pk;
            }
        }
    } else {
#pragma unroll
        for (int j = 0; j < JT; ++j) {
            int o = ob0 + j * 16 + l16;
            float bs = bias[o];
#pragma unroll
            for (int i = 0; i < 4; ++i) {
                int n = nb0 + i * 16 + quad * 4;
                size_t ad = ((size_t)b * Cout + o) * NN + n;
                float4 rv = *(const float4*)&res[ad];
                float4 yv;
                yv.x = acc[i][j][0] + bs + rv.x;
                yv.y = acc[i][j][1] + bs + rv.y;
                yv.z = acc[i][j][2] + bs + rv.z;
                yv.w = acc[i][j][3] + bs + rv.w;
                *(float4*)&outF[ad] = yv;
                if (mode == 2) {
                    outB[(bN + n + 0) * Cout + o] = f2b(yv.x);
                    outB[(bN + n + 1) * Cout + o] = f2b(yv.y);
                    outB[(bN + n + 2) * Cout + o] = f2b(yv.z);
                    outB[(bN + n + 3) * Cout + o] = f2b(yv.w);
                }
            }
        }
    }
}

template<int JT>
__global__ __launch_bounds__(256, 3) void gemm_bf16_t(
    const u16* __restrict__ Wb, const float* __restrict__ bias,
    const u16* __restrict__ Xa, const u16* __restrict__ Xb,
    int Ca, int K, int Cout,
    const float* __restrict__ res, float* __restrict__ outF,
    u16* __restrict__ outB, int mode)
{
    __shared__ u16 As[2 * 128 * 64];
    __shared__ u16 Bs[2 * JT * 32 * 64];
    const int b = blockIdx.z, n0 = blockIdx.x * 128, o0 = blockIdx.y * (JT * 32);
    f32x4 acc[4][JT] = {};
    gemm_core_t<JT, true>(Xa, Xb, Ca, K, Wb + (size_t)o0 * K, (size_t)b * NN + n0, As, Bs, acc);
    gemm_epilogue_t<JT>(acc, bias, mode, b, n0, o0, Cout, res, outF, outB);
}

// ---------------------------------------------------------------------------
// 8-wave GEMM core (QKV / W1 path): 128(n) x 128(o) x 64(k) per block.
// ---------------------------------------------------------------------------
template<bool DBUF>
__device__ __forceinline__ void gemm_core8(
    const u16* __restrict__ Xa, const u16* __restrict__ Xb, int Ca, int K,
    const u16* __restrict__ Wt, size_t rowBase,
    u16* As, u16* Bs, f32x4 (&acc)[4][2])
{
    constexpr int ASZ = 128 * 64, BSZ = 128 * 64;
    const int tid = threadIdx.x;
    const int lane = tid & 63, w = tid >> 6;
    const int quad = lane >> 4, l16 = lane & 15;
    const int wr = w & 1, wc = w >> 1;
    const int arow = lane >> 3, aseg = lane & 7;
    const int asw = aseg ^ arow;
    const int lk = l16 & 7;

    auto stage = [&](int k0, u16* Ad, u16* Bd) {
        const u16* Xs; int Crow, cc;
        if (k0 < Ca) { Xs = Xa; Crow = Ca; cc = k0; }
        else         { Xs = Xb; Crow = K - Ca; cc = k0 - Ca; }
#pragma unroll
        for (int i = 0; i < 2; ++i) {
            int rl = w * 16 + i * 8 + arow;
            int la = __builtin_amdgcn_readfirstlane((w * 16 + i * 8) * 64);
            GLD16(Xs + (rowBase + rl) * (size_t)Crow + cc + asw * 8, (char*)Ad + (size_t)la * 2);
            GLD16(Wt + (size_t)rl * K + k0 + asw * 8, (char*)Bd + (size_t)la * 2);
        }
    };
    auto compute = [&](const u16* Ac, const u16* Bc) {
#pragma unroll
        for (int kk = 0; kk < 2; ++kk) {
            const int g = ((kk * 4 + quad) ^ lk) * 8;
            bf16x8 av[4], bv[2];
#pragma unroll
            for (int i = 0; i < 4; ++i)
                av[i] = *(const bf16x8*)&Ac[(wr * 64 + i * 16 + l16) * 64 + g];
#pragma unroll
            for (int j = 0; j < 2; ++j)
                bv[j] = *(const bf16x8*)&Bc[(wc * 32 + j * 16 + l16) * 64 + g];
#pragma unroll
            for (int i = 0; i < 4; ++i)
#pragma unroll
                for (int j = 0; j < 2; ++j)
                    acc[i][j] = __builtin_amdgcn_mfma_f32_16x16x32_bf16(av[i], bv[j], acc[i][j], 0, 0, 0);
        }
    };

    if constexpr (DBUF) {
        stage(0, As, Bs);
        const int nt = K / 64;
        for (int t = 0; t < nt; ++t) {
            const u16* Ac = As + (t & 1) * ASZ;
            const u16* Bc = Bs + (t & 1) * BSZ;
            __syncthreads();
            if (t + 1 < nt)
                stage((t + 1) * 64, As + ((t + 1) & 1) * ASZ, Bs + ((t + 1) & 1) * BSZ);
            compute(Ac, Bc);
        }
    } else {
        for (int k0 = 0; k0 < K; k0 += 64) {
            stage(k0, As, Bs);
            __syncthreads();
            compute(As, Bs);
            __syncthreads();
        }
    }
}

// modes 0/1 (QKV path)
__device__ __forceinline__ void gemm_epilogue8(
    f32x4 (&acc)[4][2], const float* __restrict__ bias, int mode,
    int b, int n0, int o0, int Cout, u16* __restrict__ outB)
{
    const int tid = threadIdx.x;
    const int lane = tid & 63, w = tid >> 6;
    const int quad = lane >> 4, l16 = lane & 15;
    const int wr = w & 1, wc = w >> 1;
    const size_t bN = (size_t)b * NN;
    const int nb0 = n0 + wr * 64, ob0 = o0 + wc * 32;

    if (mode == 0) {
#pragma unroll
        for (int j = 0; j < 2; ++j) {
            int o = ob0 + j * 16 + l16;
            float bs = bias[o];
#pragma unroll
            for (int i = 0; i < 4; ++i)
#pragma unroll
                for (int r = 0; r < 4; ++r) {
                    int n = nb0 + i * 16 + quad * 4 + r;
                    outB[(bN + n) * Cout + o] = f2b(acc[i][j][r] + bs);
                }
        }
    } else {
#pragma unroll
        for (int j = 0; j < 2; ++j) {
            int o = ob0 + j * 16 + l16;
            float bs = bias[o];
            int h = o >> 6, d = o & 63;
#pragma unroll
            for (int i = 0; i < 4; ++i) {
                int n = nb0 + i * 16 + quad * 4;
                ushort4 pk;
                pk.x = f2b(acc[i][j][0] + bs); pk.y = f2b(acc[i][j][1] + bs);
                pk.z = f2b(acc[i][j][2] + bs); pk.w = f2b(acc[i][j][3] + bs);
                *(ushort4*)&outB[(((size_t)b * HH + h) * DD + d) * NN + n] = pk;
            }
        }
    }
}

// Fused Q+K+V, 8-wave dbuf: yb<4 -> Q from XQ; 4..7 -> K from XKV; 8..11 -> V.
__global__ __launch_bounds__(512, 4) void gemm_qkv(
    const u16* __restrict__ WQ, const float* __restrict__ bQ,
    const u16* __restrict__ XQ, u16* __restrict__ outQ,
    const u16* __restrict__ WK, const float* __restrict__ bK, u16* __restrict__ outK,
    const u16* __restrict__ WV, const float* __restrict__ bV, u16* __restrict__ outV,
    const u16* __restrict__ XKV)
{
    __shared__ u16 As[2 * 128 * 64];
    __shared__ u16 Bs[2 * 128 * 64];
    const int yb = blockIdx.y;
    const u16* W; const float* bias; const u16* X; u16* outB; int mode, o0;
    if (yb < 4)      { o0 = yb * 128;       W = WQ; bias = bQ; X = XQ;  outB = outQ; mode = 0; }
    else if (yb < 8) { o0 = (yb - 4) * 128; W = WK; bias = bK; X = XKV; outB = outK; mode = 0; }
    else             { o0 = (yb - 8) * 128; W = WV; bias = bV; X = XKV; outB = outV; mode = 1; }
    const int b = blockIdx.z, n0 = blockIdx.x * 128;
    f32x4 acc[4][2] = {};
    gemm_core8<true>(X, nullptr, 512, 512, W + (size_t)o0 * 512, (size_t)b * NN + n0, As, Bs, acc);
    gemm_epilogue8(acc, bias, mode, b, n0, o0, 512, outB);
}

// W1 GEMM, 8-wave dbuf, instance-norm statistics fused into the epilogue.
__global__ __launch_bounds__(512, 4) void gemm_w1(
    const u16* __restrict__ Wb, const float* __restrict__ bias,
    const u16* __restrict__ Xa, const u16* __restrict__ Xb,
    u16* __restrict__ outB, float* __restrict__ Ssum, float* __restrict__ Ssq)
{
    __shared__ u16 As[2 * 128 * 64];
    __shared__ u16 Bs[2 * 128 * 64];
    const int b = blockIdx.z, n0 = blockIdx.x * 128, o0 = blockIdx.y * 128;
    f32x4 acc[4][2] = {};
    gemm_core8<true>(Xa, Xb, 512, 1024, Wb + (size_t)o0 * 1024, (size_t)b * NN + n0, As, Bs, acc);

    const int tid = threadIdx.x;
    const int lane = tid & 63, w = tid >> 6;
    const int quad = lane >> 4, l16 = lane & 15;
    const int wr = w & 1, wc = w >> 1;
    const size_t bN = (size_t)b * NN;
    const int nb0 = n0 + wr * 64, ob0 = o0 + wc * 32;

#pragma unroll
    for (int j = 0; j < 2; ++j) {
        int o = ob0 + j * 16 + l16;
        float bs = bias[o];
        float s = 0.f, q = 0.f;
#pragma unroll
        for (int i = 0; i < 4; ++i)
#pragma unroll
            for (int r = 0; r < 4; ++r) {
                int n = nb0 + i * 16 + quad * 4 + r;
                float y = acc[i][j][r] + bs;
                s += y; q += y * y;
                outB[(bN + n) * 1024 + o] = f2b(y);
            }
        s += __shfl_xor(s, 16); s += __shfl_xor(s, 32);   // sum over quad -> 64 rows
        q += __shfl_xor(q, 16); q += __shfl_xor(q, 32);
        if (quad == 0) {
            atomicAdd(&Ssum[b * 1024 + o], s);
            atomicAdd(&Ssq[b * 1024 + o], q);
        }
    }
}

// ---------------------------------------------------------------------------
// Flash attention, MFMA, no max-shift (scores O(1), softmax shift-invariant).
// Q pre-scaled by 0.125*log2e at weight-prep -> p = exp2(s) directly.
// R12 = R11/R9 attn unchanged (stable 44-46.4 us; best measured).
// 8 waves = 4 q-groups x 2 kv-halves; K/V double-buffered via
// global_load_lds, XOR-swizzled 16B granules; prefetch right after each
// barrier. Merge stride 44 floats. Grid 512 XCD-swizzled (4 heads/XCD).
// ---------------------------------------------------------------------------
__global__ __launch_bounds__(512, 4) void attn(
    const u16* __restrict__ Qg, const u16* __restrict__ Kg,
    const u16* __restrict__ Vg, u16* __restrict__ Og)
{
    __shared__ __align__(16) u16 pool[6 * 4096];   // Ks0|Ks1|Vt0|Vt1|Ps(128x64) = 48KB
    u16* const Ksb[2] = { pool, pool + 4096 };
    u16* const Vtb[2] = { pool + 2 * 4096, pool + 3 * 4096 };
    u16* const Ps = pool + 4 * 4096;
    const int tid = threadIdx.x;
    const int lane = tid & 63, w = tid >> 6;       // 8 waves
    const int qg = w & 3, hv = w >> 2;             // q-group, kv-half
    const int quad = lane >> 4, l16 = lane & 15;
    const int id = blockIdx.x;
    const int xcd = id & 7, jj = id >> 3;          // jj 0..63
    const int bh = xcd * 4 + (jj >> 4), nb = jj & 15;
    const int b = bh >> 3, h = bh & 7;
    const int n0 = nb * 128, wn0 = qg * 32;        // 32 q-cols per wave
    const int sr0 = w * 8;                         // staging rows for this wave
    const size_t qkBase = ((size_t)b * NN) * CC + h * DD;
    const size_t vBase  = (((size_t)b * HH + h) * DD) * NN;
    const int r8 = lane >> 3, seg = lane & 7;      // staging: 8 rows x 8x16B per wave
    const int segp = seg ^ r8;                     // write-side swizzle
    const int lk = l16 & 7;                        // read-side swizzle key

    const u16* kp = Kg + qkBase + (size_t)(sr0 + r8) * CC + segp * 8;
    const u16* vp = Vg + vBase + (size_t)(sr0 + r8) * NN + segp * 8;

    bf16x8 qf[2][2];
#pragma unroll
    for (int qs = 0; qs < 2; ++qs) {
        int n = n0 + wn0 + qs * 16 + l16;
#pragma unroll
        for (int ks = 0; ks < 2; ++ks)
            qf[qs][ks] = *(const bf16x8*)&Qg[qkBase + (size_t)n * CC + ks * 32 + quad * 8];
    }

    const short oneb = 0x3F80;
    const bf16x8 ones = {oneb, oneb, oneb, oneb, oneb, oneb, oneb, oneb};
    f32x4 oa[2][4] = {};
    f32x4 lacc[2] = {};

    GLD16(kp, Ksb[0] + sr0 * 64);
    GLD16(vp, Vtb[0] + sr0 * 64);
    kp += 64 * CC; vp += 64;

#define ATTN_PREF(BUF) do { \
        GLD16(kp, Ksb[BUF] + sr0 * 64); \
        GLD16(vp, Vtb[BUF] + sr0 * 64); \
        kp += 64 * CC; vp += 64; \
    } while (0)

#define ATTN_BODY(CUR) do { \
        const u16* ksb = Ksb[CUR]; \
        const u16* vtb = Vtb[CUR]; \
        f32x4 st[2][2] = {}; \
        _Pragma("unroll") \
        for (int ks = 0; ks < 2; ++ks) { \
            bf16x8 ak[2]; \
            _Pragma("unroll") \
            for (int rtl = 0; rtl < 2; ++rtl) \
                ak[rtl] = *(const bf16x8*)&ksb[(hv * 32 + rtl * 16 + l16) * 64 + ((ks * 4 + quad) ^ lk) * 8]; \
            __builtin_amdgcn_s_setprio(1); \
            _Pragma("unroll") \
            for (int rtl = 0; rtl < 2; ++rtl) \
                _Pragma("unroll") \
                for (int qs = 0; qs < 2; ++qs) \
                    st[qs][rtl] = __builtin_amdgcn_mfma_f32_16x16x32_bf16(ak[rtl], qf[qs][ks], st[qs][rtl], 0, 0, 0); \
            __builtin_amdgcn_s_setprio(0); \
        } \
        _Pragma("unroll") \
        for (int qs = 0; qs < 2; ++qs) { \
            int nrow = wn0 + qs * 16 + l16; \
            _Pragma("unroll") \
            for (int rtl = 0; rtl < 2; ++rtl) { \
                unsigned u0 = __builtin_bit_cast(unsigned, __ocml_native_exp2_f32(st[qs][rtl][0])); \
                unsigned u1 = __builtin_bit_cast(unsigned, __ocml_native_exp2_f32(st[qs][rtl][1])); \
                unsigned u2 = __builtin_bit_cast(unsigned, __ocml_native_exp2_f32(st[qs][rtl][2])); \
                unsigned u3 = __builtin_bit_cast(unsigned, __ocml_native_exp2_f32(st[qs][rtl][3])); \
                uint2 t; \
                t.x = __builtin_amdgcn_perm(u1, u0, 0x07060302u); \
                t.y = __builtin_amdgcn_perm(u3, u2, 0x07060302u); \
                int g = (((hv * 2 + rtl) * 2 + (quad >> 1))) ^ lk; \
                *(uint2*)&Ps[nrow * 64 + g * 8 + (quad & 1) * 4] = t; \
            } \
        } \
        { \
            bf16x8 pa[2]; \
            _Pragma("unroll") \
            for (int qs = 0; qs < 2; ++qs) \
                pa[qs] = *(const bf16x8*)&Ps[(wn0 + qs * 16 + l16) * 64 + ((hv * 4 + quad) ^ lk) * 8]; \
            bf16x8 vb[4]; \
            _Pragma("unroll") \
            for (int ct = 0; ct < 4; ++ct) \
                vb[ct] = *(const bf16x8*)&vtb[(ct * 16 + l16) * 64 + ((hv * 4 + quad) ^ lk) * 8]; \
            __builtin_amdgcn_s_setprio(1); \
            _Pragma("unroll") \
            for (int ct = 0; ct < 4; ++ct) \
                _Pragma("unroll") \
                for (int qs = 0; qs < 2; ++qs) \
                    oa[qs][ct] = __builtin_amdgcn_mfma_f32_16x16x32_bf16(pa[qs], vb[ct], oa[qs][ct], 0, 0, 0); \
            _Pragma("unroll") \
            for (int qs = 0; qs < 2; ++qs) \
                lacc[qs] = __builtin_amdgcn_mfma_f32_16x16x32_bf16(pa[qs], ones, lacc[qs], 0, 0, 0); \
            __builtin_amdgcn_s_setprio(0); \
        } \
    } while (0)

    for (int it = 0; it < NN / 64; it += 2) {
        __syncthreads();
        ATTN_PREF(1);
        ATTN_BODY(0);
        __syncthreads();
        if (it < NN / 64 - 2)
            ATTN_PREF(0);
        ATTN_BODY(1);
    }
#undef ATTN_PREF
#undef ATTN_BODY

    // merge the two kv-halves' partial O and l via LDS (pool is dead now)
    __syncthreads();
    float* M = (float*)pool;                       // stride 44 floats: 16B-aligned, ~2-way
    const int mbase = (qg * 64 + lane) * 44;
    if (hv == 1) {
#pragma unroll
        for (int qs = 0; qs < 2; ++qs)
#pragma unroll
            for (int ct = 0; ct < 4; ++ct)
                *(f32x4*)&M[mbase + (qs * 4 + ct) * 4] = oa[qs][ct];
        *(f32x4*)&M[mbase + 32] = lacc[0];
        *(f32x4*)&M[mbase + 36] = lacc[1];
    }
    __syncthreads();
    if (hv == 0) {
#pragma unroll
        for (int qs = 0; qs < 2; ++qs)
#pragma unroll
            for (int ct = 0; ct < 4; ++ct)
                oa[qs][ct] += *(const f32x4*)&M[mbase + (qs * 4 + ct) * 4];
        lacc[0] += *(const f32x4*)&M[mbase + 32];
        lacc[1] += *(const f32x4*)&M[mbase + 36];
#pragma unroll
        for (int qs = 0; qs < 2; ++qs)
#pragma unroll
            for (int r = 0; r < 4; ++r) {
                float li = 1.f / lacc[qs][r];
                int n = n0 + wn0 + qs * 16 + quad * 4 + r;
#pragma unroll
                for (int ct = 0; ct < 4; ++ct)
                    Og[qkBase + (size_t)n * CC + ct * 16 + l16] = f2b(oa[qs][ct][r] * li);
            }
    }
}

// ---------------------------------------------------------------------------
// fp32 [B,C,N] -> bf16 [B,N,C] transpose+convert (64x64 tiles via LDS).
// R12: src and tgt merged into ONE dispatch (grid z = 8: z<4 src->Y0,
// z>=4 tgt->Y1) — one fewer stream-serialized launch.
// ---------------------------------------------------------------------------
__global__ __launch_bounds__(256) void transpose_cvt2(
    const float* __restrict__ Xs, const float* __restrict__ Xt,
    u16* __restrict__ Y0, u16* __restrict__ Y1)
{
    __shared__ float T[64][65];
    const int tid = threadIdx.x;
    const int z = blockIdx.z;
    const float* X = (z < 4) ? Xs : Xt;
    u16* Y = (z < 4) ? Y0 : Y1;
    const int b = z & 3;
    const int n0 = blockIdx.x * 64, c0 = blockIdx.y * 64;
    const int rr = tid >> 4, cc4 = tid & 15;
#pragma unroll
    for (int p = 0; p < 4; ++p) {
        int cl = p * 16 + rr;
        float4 v = *(const float4*)&X[((size_t)b * CC + c0 + cl) * NN + n0 + cc4 * 4];
        T[cl][cc4 * 4 + 0] = v.x; T[cl][cc4 * 4 + 1] = v.y;
        T[cl][cc4 * 4 + 2] = v.z; T[cl][cc4 * 4 + 3] = v.w;
    }
    __syncthreads();
#pragma unroll
    for (int p = 0; p < 4; ++p) {
        int nl = p * 16 + rr;
        ushort4 pk;
        pk.x = f2b(T[cc4 * 4 + 0][nl]);
        pk.y = f2b(T[cc4 * 4 + 1][nl]);
        pk.z = f2b(T[cc4 * 4 + 2][nl]);
        pk.w = f2b(T[cc4 * 4 + 3][nl]);
        *(ushort4*)&Y[((size_t)b * NN + n0 + nl) * CC + c0 + cc4 * 4] = pk;
    }
}

// ---------------------------------------------------------------------------
// One-shot weight prep: fp32->bf16 with optional row/col head-permute + scale.
// R12: vectorized x4 — float4 read + ushort4 write for perm 0/1 (row-permute
// keeps columns contiguous); gather-read + ushort4 write for perm 2.
// ---------------------------------------------------------------------------
__global__ __launch_bounds__(256) void prep_weights(
    const float* __restrict__ Wq, const float* __restrict__ Wk,
    const float* __restrict__ Wv, const float* __restrict__ Wm,
    const float* __restrict__ W1, const float* __restrict__ W2,
    u16* oQ, u16* oK, u16* oV, u16* oM, u16* o1, u16* o2)
{
    const float* W; u16* o; int rows, cols, perm; float sc = 1.f;
    switch (blockIdx.z) {
        case 0: W = Wq; o = oQ; rows = 512;  cols = 512;  perm = 1; sc = SCALE; break;
        case 1: W = Wk; o = oK; rows = 512;  cols = 512;  perm = 1; break;
        case 2: W = Wv; o = oV; rows = 512;  cols = 512;  perm = 1; break;
        case 3: W = Wm; o = oM; rows = 512;  cols = 512;  perm = 2; break;
        case 4: W = W1; o = o1; rows = 1024; cols = 1024; perm = 0; break;
        default: W = W2; o = o2; rows = 512; cols = 1024; perm = 0; break;
    }
    int c4 = (blockIdx.x * 256 + threadIdx.x) * 4;
    int r = blockIdx.y;
    if (r >= rows || c4 >= cols) return;
    int sr = (perm == 1) ? ((r & 63) * 8 + (r >> 6)) : r;
    ushort4 pk;
    if (perm == 2) {
        u16 tmp[4];
#pragma unroll
        for (int t = 0; t < 4; ++t) {
            int c = c4 + t;
            int scol = (c & 63) * 8 + (c >> 6);
            tmp[t] = f2b(W[(size_t)sr * cols + scol]);
        }
        pk.x = tmp[0]; pk.y = tmp[1]; pk.z = tmp[2]; pk.w = tmp[3];
    } else {
        float4 v = *(const float4*)&W[(size_t)sr * cols + c4];
        pk.x = f2b(v.x * sc); pk.y = f2b(v.y * sc);
        pk.z = f2b(v.z * sc); pk.w = f2b(v.w * sc);
    }
    *(ushort4*)&o[(size_t)r * cols + c4] = pk;
}

// ---------------------------------------------------------------------------
// Bias prep + stat-buffer zeroing (R12: both hipMemsetAsync dispatches
// folded in here — y==3 zeroes the 4 stat buffers, 16384 floats).
// grid (16, 4) x 256.
// ---------------------------------------------------------------------------
__global__ void prep_bias(const float* __restrict__ bq, const float* __restrict__ bk,
                          const float* __restrict__ bv,
                          float* oq, float* ok, float* ov, float* stats)
{
    int i = blockIdx.x * 256 + threadIdx.x;
    int y = blockIdx.y;
    if (y == 3) {
        *(float4*)&stats[(size_t)i * 4] = float4{0.f, 0.f, 0.f, 0.f};
        return;
    }
    if (i >= 512) return;
    const float* s = (y == 0) ? bq : (y == 1) ? bk : bv;
    float* o = (y == 0) ? oq : (y == 1) ? ok : ov;
    float v = s[(i & 63) * 8 + (i >> 6)];
    if (y == 0) v *= SCALE;
    o[i] = v;
}

// ---------------------------------------------------------------------------
// Instance-norm apply (+ReLU) on bf16 [B,N,1024], in place. Vectorized
// bf16x8, 256 threads, grid (128 nz, 4 b) = 512 blocks.
// ---------------------------------------------------------------------------
__global__ __launch_bounds__(256) void inorm_p2(
    u16* __restrict__ X, const float* __restrict__ Ssum, const float* __restrict__ Ssq)
{
    const int tid = threadIdx.x;
    const int cidx = (tid & 127) * 8;
    const int rq = tid >> 7;              // 0..1
    const int b = blockIdx.y, nz = blockIdx.x;
    float4 s0 = *(const float4*)&Ssum[b * 1024 + cidx];
    float4 s1 = *(const float4*)&Ssum[b * 1024 + cidx + 4];
    float4 q0 = *(const float4*)&Ssq[b * 1024 + cidx];
    float4 q1 = *(const float4*)&Ssq[b * 1024 + cidx + 4];
    float mean[8] = { s0.x, s0.y, s0.z, s0.w, s1.x, s1.y, s1.z, s1.w };
    float sq[8]   = { q0.x, q0.y, q0.z, q0.w, q1.x, q1.y, q1.z, q1.w };
    float rstd[8];
#pragma unroll
    for (int j = 0; j < 8; ++j) {
        float m = mean[j] * (1.f / NN);
        float v = sq[j] * (1.f / NN) - m * m;
        mean[j] = m; rstd[j] = rsqrtf(fmaxf(v, 0.f) + 1e-5f);
    }
    size_t base = ((size_t)b * NN + nz * 16 + rq * 8) * 1024 + cidx;
    for (int i = 0; i < 8; ++i) {
        bf16x8 v = *(const bf16x8*)&X[base + (size_t)i * 1024];
        bf16x8 o;
#pragma unroll
        for (int j = 0; j < 8; ++j) {
            float x = b2f((u16)v[j]);
            x = (x - mean[j]) * rstd[j];
            o[j] = (short)f2b(fmaxf(x, 0.f));
        }
        *(bf16x8*)&X[base + (size_t)i * 1024] = o;
    }
}

// ---------------------------------------------------------------------------
extern "C" void kernel_launch(void* const* d_in, const int* in_sizes, int n_in,
                              void* d_out, int out_size, void* d_ws, size_t ws_size,
                              hipStream_t stream)
{
    (void)in_sizes; (void)n_in; (void)out_size; (void)ws_size;
    const float* src = (const float*)d_in[0];
    const float* tgt = (const float*)d_in[1];
    const float* Wq = (const float*)d_in[2];  const float* bq = (const float*)d_in[3];
    const float* Wk = (const float*)d_in[4];  const float* bk = (const float*)d_in[5];
    const float* Wv = (const float*)d_in[6];  const float* bv = (const float*)d_in[7];
    const float* Wm = (const float*)d_in[8];  const float* bm = (const float*)d_in[9];
    const float* W1 = (const float*)d_in[10]; const float* b1 = (const float*)d_in[11];
    const float* W2 = (const float*)d_in[12]; const float* b2 = (const float*)d_in[13];

    char* w = (char*)d_ws;
    u16* WQp = (u16*)(w);
    u16* WKp = (u16*)(w + (512u << 10));
    u16* WVp = (u16*)(w + (1u << 20));
    u16* WMp = (u16*)(w + (3u << 19));
    u16* W1b = (u16*)(w + (2u << 20));
    u16* W2b = (u16*)(w + (4u << 20));
    float* BQp = (float*)(w + (5u << 20));
    float* BKp = BQp + 512;
    float* BVp = BQp + 1024;
    float* STS  = BQp + 1536;              // pipeline-1 stats: sum | sq
    float* STQ  = STS + 4096;
    float* STS2 = STQ + 4096;              // pipeline-2 stats: sum | sq
    float* STQ2 = STS2 + 4096;
    u16* X0 = (u16*)(w + ( 6u << 20));        // 8 MB regions
    u16* X1 = (u16*)(w + (14u << 20));
    u16* B0 = (u16*)(w + (22u << 20));
    u16* B1 = (u16*)(w + (30u << 20));
    u16* B2 = (u16*)(w + (38u << 20));
    u16* B3 = (u16*)(w + (46u << 20));

    float* out = (float*)d_out;
    const size_t R = (size_t)BB * CC * NN;
    dim3 blk(256), blkA(512);

    prep_weights<<<dim3(1, 1024, 6), blk, 0, stream>>>(Wq, Wk, Wv, Wm, W1, W2,
                                                       WQp, WKp, WVp, WMp, W1b, W2b);
    prep_bias<<<dim3(16, 4), blk, 0, stream>>>(bq, bk, bv, BQp, BKp, BVp, STS);
    transpose_cvt2<<<dim3(32, 8, 8), blk, 0, stream>>>(src, tgt, X0, X1);

    dim3 gQKV(16, 12, 4), gM(16, 8, 4), gW1(16, 8, 4), gW2(16, 8, 4), gIN(128, 4);

    // ---- pipeline 1: q<-src(X0), k/v<-tgt(X1), residual=src ----
    gemm_qkv<<<gQKV, blkA, 0, stream>>>(WQp, BQp, X0, B0, WKp, BKp, B1, WVp, BVp, B2, X1);
    attn<<<dim3(512), blkA, 0, stream>>>(B0, B1, B2, B3);
    gemm_bf16_t<2><<<gM, blk, 0, stream>>>(WMp, bm, B3, nullptr, 512, 512, 512, nullptr, nullptr, B0, 0);
    gemm_w1<<<gW1, blkA, 0, stream>>>(W1b, b1, X0, B0, B1, STS, STQ);
    inorm_p2<<<gIN, blk, 0, stream>>>(B1, STS, STQ);
    gemm_bf16_t<2><<<gW2, blk, 0, stream>>>(W2b, b2, B1, nullptr, 1024, 1024, 512, src, out, B3, 2);

    // ---- pipeline 2: q<-tgt(X1), k/v<-src_new(B3), residual=tgt ----
    gemm_qkv<<<gQKV, blkA, 0, stream>>>(WQp, BQp, X1, X0, WKp, BKp, B0, WVp, BVp, B1, B3);
    attn<<<dim3(512), blkA, 0, stream>>>(X0, B0, B1, B2);
    gemm_bf16_t<2><<<gM, blk, 0, stream>>>(WMp, bm, B2, nullptr, 512, 512, 512, nullptr, nullptr, X0, 0);
    gemm_w1<<<gW1, blkA, 0, stream>>>(W1b, b1, X1, X0, B0, STS2, STQ2);
    inorm_p2<<<gIN, blk, 0, stream>>>(B0, STS2, STQ2);
    gemm_bf16_t<2><<<gW2, blk, 0, stream>>>(W2b, b2, B0, nullptr, 1024, 1024, 512, tgt, out + R, nullptr, 3);
}